// Round 3
// baseline (739.034 us; speedup 1.0000x reference)
//
#include <hip/hip_runtime.h>
#include <hip/hip_bf16.h>
#include <cstdint>

#define NN 256
#define NB 4
#define OC 128

using bf16x8_t = __attribute__((ext_vector_type(8))) __bf16;
using f32x4_t  = __attribute__((ext_vector_type(4))) float;
using f32x16_t = __attribute__((ext_vector_type(16))) float;

typedef const __attribute__((address_space(1))) uint8_t* gptr1_t;
typedef __attribute__((address_space(3))) uint8_t* lptr3_t;

__device__ __forceinline__ void async_load16(const void* g, void* l) {
  __builtin_amdgcn_global_load_lds((gptr1_t)g, (lptr3_t)l, 16, 0, 0);
}

// sigmoid via v_rcp_f32 (1-ulp) instead of the precise-div sequence
__device__ __forceinline__ float sigf(float x) {
  return __builtin_amdgcn_rcpf(1.0f + __expf(-x));
}

__device__ __forceinline__ uint16_t f2bf_rne(float f) {
  uint32_t u = __float_as_uint(f);
  uint32_t r = (u + 0x7fffu + ((u >> 16) & 1u)) >> 16;
  return (uint16_t)r;
}

// ---------------------------------------------------------------------------
// prep (weights transpose/pack, g1bf0 static slots, r2 init)  +  reduce2 L0.
// ---------------------------------------------------------------------------
__device__ __forceinline__ void emit_wt(const float* __restrict__ W2,
                                        uint16_t* __restrict__ Wt, int d1,
                                        int d2, int idx) {
  const int K = 2 * d2;
  const int nn = idx / K, k = idx - nn * K;
  const int row = (k < d2) ? (d1 + k) : (2 * d1 + d2 + (k - d2));
  Wt[idx] = f2bf_rne(W2[row * OC + nn]);
}

__device__ __forceinline__ void emit_bt(const float* __restrict__ W1,
                                        const float* __restrict__ W2,
                                        uint16_t* __restrict__ Bt, int D0,
                                        int D1, int D2, int FIN1, int KP,
                                        int idx) {
  const int n = idx / KP, k = idx - n * KP;
  float val = 0.f;
  if (n < 128) {
    if (k < FIN1) val = W1[k * OC + n];
  } else if (n < 256) {
    if (k >= D0 && k < D0 + D1) val = W2[(k - D0) * OC + (n - 128)];
  } else {
    if (k >= D0 && k < D0 + D1) val = W2[(D1 + D2 + (k - D0)) * OC + (n - 256)];
  }
  Bt[idx] = f2bf_rne(val);
}

__global__ __launch_bounds__(256) void prep_reduce(
    const float* __restrict__ W2_0, const float* __restrict__ W2_1,
    const float* __restrict__ W2_2, const float* __restrict__ W1_0,
    const float* __restrict__ W1_1, const float* __restrict__ W1_2,
    const float* __restrict__ x0, const float* __restrict__ x1,
    uint16_t* __restrict__ Wt0, uint16_t* __restrict__ Wt1,
    uint16_t* __restrict__ Wt2, uint16_t* __restrict__ Bt0,
    uint16_t* __restrict__ Bt1, uint16_t* __restrict__ Bt2,
    uint16_t* __restrict__ g1bf0, float* __restrict__ r2b,
    float* __restrict__ r2c, const float* __restrict__ x2,
    uint16_t* __restrict__ x2bf) {
  __shared__ float4 smx[256], smn[256];
  const int blk = blockIdx.x;
  const int tid = threadIdx.x;

  if (blk < 4800) {  // ---- prep part ----
    int g = blk * 256 + tid;
    if (g < 16384) { emit_wt(W2_0, Wt0, 64, 64, g); return; }
    g -= 16384;
    if (g < 32768) { emit_wt(W2_1, Wt1, 128, 128, g); return; }
    g -= 32768;
    if (g < 32768) { emit_wt(W2_2, Wt2, 128, 128, g); return; }
    g -= 32768;
    if (g < 98304) { emit_bt(W1_0, W2_0, Bt0, 32, 64, 64, 224, 256, g); return; }
    g -= 98304;
    if (g < 196608) { emit_bt(W1_1, W2_1, Bt1, 128, 128, 128, 512, 512, g); return; }
    g -= 196608;
    if (g < 196608) { emit_bt(W1_2, W2_2, Bt2, 128, 128, 128, 512, 512, g); return; }
    g -= 196608;
    if (g < 131072) {  // g1bf0 static slots: f0[0..32) f1[32..96) pad[224..256)
      const int row = g >> 7, t = g & 127;
      uint16_t* const gp = g1bf0 + (size_t)row * 256;
      if (t < 32) gp[t] = f2bf_rne(x0[(row >> 8) * 32 + t]);
      else if (t < 96) gp[t] = f2bf_rne(x1[(size_t)row * 64 + (t - 32)]);
      else gp[128 + t] = 0;
      return;
    }
    g -= 131072;
    if (g < 262144) { r2b[g] = ((g & 255) < 128) ? 0.f : 1.f; return; }
    g -= 262144;
    if (g < 262144) { r2c[g] = ((g & 255) < 128) ? 0.f : 1.f; }
    return;
  }

  // ---- reduce2 layer 0: fp32 x2 -> bf16 x2bf + max/min into g1bf0 ----
  const int bid = blk - 4800;               // b*256 + i
  const int i = bid & 255;
  const int q = tid & 15, s = tid >> 4;
  const size_t rowbase = ((size_t)bid * NN) * 64 + q * 4;
  float mxA0 = 0.f, mxA1 = 0.f, mxA2 = 0.f, mxA3 = 0.f;
  float mnA0 = 1.f, mnA1 = 1.f, mnA2 = 1.f, mnA3 = 1.f;
  float mxB0 = 0.f, mxB1 = 0.f, mxB2 = 0.f, mxB3 = 0.f;
  float mnB0 = 1.f, mnB1 = 1.f, mnB2 = 1.f, mnB3 = 1.f;
#pragma unroll 2
  for (int t = 0; t < 16; t += 2) {
    const int jA = s + t * 16, jB = jA + 16;
    const float4 xa = *(const float4*)(x2 + rowbase + (size_t)jA * 64);
    const float4 xb = *(const float4*)(x2 + rowbase + (size_t)jB * 64);
    uint2 pa, pb;
    pa.x = (uint32_t)f2bf_rne(xa.x) | ((uint32_t)f2bf_rne(xa.y) << 16);
    pa.y = (uint32_t)f2bf_rne(xa.z) | ((uint32_t)f2bf_rne(xa.w) << 16);
    pb.x = (uint32_t)f2bf_rne(xb.x) | ((uint32_t)f2bf_rne(xb.y) << 16);
    pb.y = (uint32_t)f2bf_rne(xb.z) | ((uint32_t)f2bf_rne(xb.w) << 16);
    *(uint2*)(x2bf + rowbase + (size_t)jA * 64) = pa;
    *(uint2*)(x2bf + rowbase + (size_t)jB * 64) = pb;
    if (jA != i) {
      mxA0 = fmaxf(mxA0, xa.x); mxA1 = fmaxf(mxA1, xa.y);
      mxA2 = fmaxf(mxA2, xa.z); mxA3 = fmaxf(mxA3, xa.w);
      mnA0 = fminf(mnA0, xa.x); mnA1 = fminf(mnA1, xa.y);
      mnA2 = fminf(mnA2, xa.z); mnA3 = fminf(mnA3, xa.w);
    }
    if (jB != i) {
      mxB0 = fmaxf(mxB0, xb.x); mxB1 = fmaxf(mxB1, xb.y);
      mxB2 = fmaxf(mxB2, xb.z); mxB3 = fmaxf(mxB3, xb.w);
      mnB0 = fminf(mnB0, xb.x); mnB1 = fminf(mnB1, xb.y);
      mnB2 = fminf(mnB2, xb.z); mnB3 = fminf(mnB3, xb.w);
    }
  }
  float mx0 = fmaxf(mxA0, mxB0), mx1 = fmaxf(mxA1, mxB1);
  float mx2 = fmaxf(mxA2, mxB2), mx3 = fmaxf(mxA3, mxB3);
  float mn0 = fminf(mnA0, mnB0), mn1 = fminf(mnA1, mnB1);
  float mn2 = fminf(mnA2, mnB2), mn3 = fminf(mnA3, mnB3);
  smx[tid] = make_float4(mx0, mx1, mx2, mx3);
  smn[tid] = make_float4(mn0, mn1, mn2, mn3);
  __syncthreads();
  if (s == 0) {
    for (int ss = 1; ss < 16; ++ss) {
      float4 a = smx[q + ss * 16], c = smn[q + ss * 16];
      mx0 = fmaxf(mx0, a.x); mx1 = fmaxf(mx1, a.y);
      mx2 = fmaxf(mx2, a.z); mx3 = fmaxf(mx3, a.w);
      mn0 = fminf(mn0, c.x); mn1 = fminf(mn1, c.y);
      mn2 = fminf(mn2, c.z); mn3 = fminf(mn3, c.w);
    }
    uint16_t* const g = g1bf0 + (size_t)bid * 256;
    g[96 + q * 4 + 0] = f2bf_rne(mx0); g[96 + q * 4 + 1] = f2bf_rne(mx1);
    g[96 + q * 4 + 2] = f2bf_rne(mx2); g[96 + q * 4 + 3] = f2bf_rne(mx3);
    g[160 + q * 4 + 0] = f2bf_rne(mn0); g[160 + q * 4 + 1] = f2bf_rne(mn1);
    g[160 + q * 4 + 2] = f2bf_rne(mn2); g[160 + q * 4 + 3] = f2bf_rne(mn3);
  }
}

// ---------------------------------------------------------------------------
// Small fused MFMA GEMM + o0 (round-0 proven LDS-staged structure).
// ---------------------------------------------------------------------------
template <int KP, int D0, int D1, bool DUP>
__global__ __launch_bounds__(256) void small_gemm(
    const uint16_t* __restrict__ g1, const uint16_t* __restrict__ Bt,
    const float* __restrict__ b1, const float* __restrict__ b2,
    float* __restrict__ f1out, uint16_t* __restrict__ g1next,
    float* __restrict__ u, float* __restrict__ vT,
    const float* __restrict__ f0in, const float* __restrict__ f1in,
    const float* __restrict__ W0, const float* __restrict__ b0,
    float* __restrict__ f0out) {
  constexpr int NCH = KP / 64;
  const int bid = blockIdx.x;
  const int tid = threadIdx.x;

  __shared__ __align__(16) uint8_t ldsA[8192];
  __shared__ __align__(16) uint8_t ldsB[16384];

  if (bid < 48) {
    const int mt = bid / 3, nt = bid - mt * 3;
    const int m0 = mt * 64, n0 = nt * 128;
    const int wv = tid >> 6, lane = tid & 63;
    const int l15 = lane & 15, l4 = lane >> 4;

    f32x4_t acc[4][2];
#pragma unroll
    for (int a = 0; a < 4; ++a)
#pragma unroll
      for (int q = 0; q < 2; ++q) acc[a][q] = (f32x4_t){0.f, 0.f, 0.f, 0.f};

    for (int c = 0; c < NCH; ++c) {
      const int kbg = c * 64;
#pragma unroll
      for (int t = 0; t < 2; ++t) {  // A units: id = ks*4 + mi
        const int id = wv * 2 + t;
        const int mi = id & 3, ks = id >> 2;
        async_load16(g1 + (size_t)(m0 + mi * 16 + l15) * KP + kbg + ks * 32 + l4 * 8,
                     ldsA + id * 1024);
      }
#pragma unroll
      for (int t = 0; t < 4; ++t) {  // B units: id = ks*8 + ni
        const int id = wv * 4 + t;
        const int ni = id & 7, ks = id >> 3;
        async_load16(Bt + (size_t)(n0 + ni * 16 + l15) * KP + kbg + ks * 32 + l4 * 8,
                     ldsB + id * 1024);
      }
      __syncthreads();
#pragma unroll
      for (int ks = 0; ks < 2; ++ks) {
        bf16x8_t Af[4], Bf[2];
#pragma unroll
        for (int a = 0; a < 4; ++a)
          Af[a] = *(const bf16x8_t*)(ldsA + ((ks * 4 + a) << 10) + (lane << 4));
#pragma unroll
        for (int q = 0; q < 2; ++q)
          Bf[q] = *(const bf16x8_t*)(ldsB + ((ks * 8 + wv * 2 + q) << 10) + (lane << 4));
#pragma unroll
        for (int a = 0; a < 4; ++a)
#pragma unroll
          for (int q = 0; q < 2; ++q)
            acc[a][q] = __builtin_amdgcn_mfma_f32_16x16x32_bf16(Af[a], Bf[q],
                                                                acc[a][q], 0, 0, 0);
      }
      __syncthreads();
    }

    float bias[2];
#pragma unroll
    for (int q = 0; q < 2; ++q) {
      const int cc = wv * 32 + q * 16 + l15;
      bias[q] = (nt == 0) ? b1[cc] : ((nt == 1) ? b2[cc] : 0.f);
    }
#pragma unroll
    for (int a = 0; a < 4; ++a) {
      const int rl = a * 16 + l4 * 4;
#pragma unroll
      for (int r = 0; r < 4; ++r) {
        const size_t bi = m0 + rl + r;
#pragma unroll
        for (int q = 0; q < 2; ++q) {
          const int cc = wv * 32 + q * 16 + l15;
          const float x = acc[a][q][r] + bias[q];
          if (nt == 0) {
            const float val = sigf(x);
            f1out[bi * OC + cc] = val;
            if (DUP) g1next[bi * 512 + 128 + cc] = f2bf_rne(val);
          } else if (nt == 1) {
            u[bi * OC + cc] = x;
          } else {
            const int b = (int)(bi >> 8), j = (int)(bi & 255);
            vT[((size_t)b * OC + cc) * NN + j] = x;
          }
        }
      }
    }
  } else {
    // ---- o0 for batch b ----
    constexpr int FIN0 = D0 + 2 * D1;
    constexpr int S = 256 / D1;
    const int b = bid - 48;
    float* const sm = (float*)ldsA;   // reuse LDS: g0 | smx | smn | sval
    float* const g0 = sm;
    float* const smx = sm + 512;
    float* const smn = sm + 768;
    float* const sval = sm + 1024;
    const int cc = tid & (D1 - 1), ss = tid / D1;
    float mx = -1e30f, mn = 1e30f;
    const float* f1b = f1in + (size_t)b * NN * D1;
    for (int j = ss; j < NN; j += S) {
      const float x = f1b[(size_t)j * D1 + cc];
      mx = fmaxf(mx, x); mn = fminf(mn, x);
    }
    smx[tid] = mx; smn[tid] = mn;
    __syncthreads();
    if (ss == 0) {
      for (int s2 = 1; s2 < S; ++s2) {
        mx = fmaxf(mx, smx[cc + s2 * D1]);
        mn = fminf(mn, smn[cc + s2 * D1]);
      }
      g0[D0 + cc] = mx;
      g0[D0 + D1 + cc] = mn;
    }
    if (tid < D0) g0[tid] = f0in[b * D0 + tid];
    __syncthreads();
    if (tid < OC) {
      float acc = b0[tid];
#pragma unroll 8
      for (int k = 0; k < FIN0; ++k) acc += g0[k] * W0[k * OC + tid];
      const float val = sigf(acc);
      f0out[b * OC + tid] = val;
      sval[tid] = val;
    }
    if (DUP) {
      __syncthreads();
      for (int idx = tid; idx < 256 * 128; idx += 256) {
        const int row = idx >> 7, c2 = idx & 127;
        g1next[((size_t)(b * 256 + row)) * 512 + c2] = f2bf_rne(sval[c2]);
      }
    }
  }
}

// ---------------------------------------------------------------------------
// conv: fp32 r2 (post gemm2 atomics) -> bf16 into g1next r2 slot [256..512).
// ---------------------------------------------------------------------------
__global__ __launch_bounds__(256) void conv_r2_kernel(
    const float* __restrict__ r2, uint16_t* __restrict__ g1next) {
  const int bi = blockIdx.x, t = threadIdx.x;
  g1next[(size_t)bi * 512 + 256 + t] = f2bf_rne(r2[(size_t)bi * 256 + t]);
}

// ---------------------------------------------------------------------------
// Big order-2 GEMM, v3: OCCUPANCY-FIRST. One 32x32 output tile per wave via
// mfma_f32_32x32x16_bf16 (acc = 16 VGPR), 4 waves/block = 32-row j-strip x
// 128 cols, grid = B*NN*8. K walked in 16-wide steps with direct-to-VGPR
// operand loads: ZERO LDS staging, ZERO barriers in the K-loop (non-REDUCE
// path has no __syncthreads at all). In-loop VGPR ~50 -> 8 waves/SIMD
// (32 waves/CU), 2x the resident waves of the 128x128 design; the compiler
// pipelines the fully-unrolled independent loads (6-8 dwordx4 in flight/wave).
// A-strip (16 KB) is shared by all 4 waves -> L1-resident; W slices L2-hit.
// C/D layout (m74/m101): col = lane&31, row = (reg&3) + 8*(reg>>2) + 4*(lane>>5).
// bf16 epilogue stores direct (L2 merges 64B sectors); no LDS staging.
// ---------------------------------------------------------------------------
template <int D2, typename OUT_T, bool REDUCE>
__global__ __launch_bounds__(256, 8) void gemm2_kernel(
    const __hip_bfloat16* __restrict__ f2, const uint16_t* __restrict__ Wt,
    const float* __restrict__ u, const float* __restrict__ vT,
    OUT_T* __restrict__ out, float* __restrict__ r2n) {
  constexpr int K = 2 * D2;
  constexpr int NST = K / 16;
  constexpr bool BF16OUT = (sizeof(OUT_T) == 2);

  const int bid = blockIdx.x;
  const int strip = bid & 7, i = (bid >> 3) & 255, b = bid >> 11;
  const int j0 = strip * 32;
  const int tid = threadIdx.x;
  const int wv = tid >> 6, lane = tid & 63;
  const int l31 = lane & 31, hi = lane >> 5;
  const int c0 = wv * 32;

  __shared__ unsigned smax[128], smin[128];

  const __hip_bfloat16* const A1 = f2 + ((size_t)(b * NN + i) * NN + j0) * D2;
  const __hip_bfloat16* const A2 = f2 + ((size_t)(b * NN + j0) * NN + i) * D2;
  const __hip_bfloat16* const Wg = (const __hip_bfloat16*)Wt;

  // per-lane element offsets (k-step offsets fold into the 13-bit imm)
  const uint32_t offA1 = (uint32_t)l31 * D2 + hi * 8;
  const uint32_t offA2 = (uint32_t)l31 * (NN * D2) + hi * 8;
  const uint32_t offW  = (uint32_t)(c0 + l31) * K + hi * 8;

  f32x16_t acc = {0.f, 0.f, 0.f, 0.f, 0.f, 0.f, 0.f, 0.f,
                  0.f, 0.f, 0.f, 0.f, 0.f, 0.f, 0.f, 0.f};

#pragma unroll
  for (int st = 0; st < NST; ++st) {
    const int kb = st * 16;
    bf16x8_t Af, Bf;
    if (kb < D2)
      Af = *(const bf16x8_t*)(A1 + offA1 + kb);
    else
      Af = *(const bf16x8_t*)(A2 + offA2 + (kb - D2));
    Bf = *(const bf16x8_t*)(Wg + offW + kb);
    acc = __builtin_amdgcn_mfma_f32_32x32x16_bf16(Af, Bf, acc, 0, 0, 0);
  }

  const size_t bi2 = (size_t)(b * NN + i);
  const int col = c0 + l31;
  const float uv = u[bi2 * OC + col];
  const float* const vTc = vT + ((size_t)b * OC + col) * NN + j0;  // 32 j's
  const size_t obase = (bi2 * NN + j0) * OC + col;

  if (BF16OUT) {
    if (REDUCE) {
      if (tid < 128) { smax[tid] = 0u; smin[tid] = 0x3f800000u; }
      __syncthreads();
    }
    float lmx = 0.f, lmn = 1.f;
    uint16_t* const outp = (uint16_t*)out;
#pragma unroll
    for (int rg = 0; rg < 4; ++rg) {
      const int rbase = rg * 8 + 4 * hi;  // row base within strip
      const float4 vq = *(const float4*)(vTc + rbase);
#pragma unroll
      for (int rr = 0; rr < 4; ++rr) {
        const int row = rbase + rr;
        const float x = acc[rg * 4 + rr] + uv + ((const float*)&vq)[rr];
        const float sg = sigf(x);
        outp[obase + (size_t)row * OC] = f2bf_rne(sg);
        if (REDUCE && (j0 + row) != i) {
          lmx = fmaxf(lmx, sg);
          lmn = fminf(lmn, sg);
        }
      }
    }
    if (REDUCE) {
      atomicMax(&smax[col], __float_as_uint(lmx));
      atomicMin(&smin[col], __float_as_uint(lmn));
      __syncthreads();
      if (tid < 128) {
        unsigned* const r2u = (unsigned*)r2n;
        atomicMax(&r2u[bi2 * 256 + tid], smax[tid]);
        atomicMin(&r2u[bi2 * 256 + 128 + tid], smin[tid]);
      }
    }
  } else {
    float* const outp = (float*)out;
#pragma unroll
    for (int rg = 0; rg < 4; ++rg) {
      const int rbase = rg * 8 + 4 * hi;
      const float4 vq = *(const float4*)(vTc + rbase);
#pragma unroll
      for (int rr = 0; rr < 4; ++rr) {
        const int row = rbase + rr;
        const float x = acc[rg * 4 + rr] + uv + ((const float*)&vq)[rr];
        outp[obase + (size_t)row * OC] = sigf(x);
      }
    }
  }
}

// ---------------------------------------------------------------------------
extern "C" void kernel_launch(void* const* d_in, const int* in_sizes, int n_in,
                              void* d_out, int out_size, void* d_ws,
                              size_t ws_size, hipStream_t stream) {
  const float* x0 = (const float*)d_in[0];
  const float* x1 = (const float*)d_in[1];
  const float* x2 = (const float*)d_in[2];
  const float *Wp[3][3], *bp[3][3];
  for (int l = 0; l < 3; ++l)
    for (int o = 0; o < 3; ++o) {
      Wp[l][o] = (const float*)d_in[3 + l * 6 + o * 2];
      bp[l][o] = (const float*)d_in[3 + l * 6 + o * 2 + 1];
    }

  const size_t F2E = (size_t)NB * NN * NN * OC;
  const size_t X2E = (size_t)NB * NN * NN * 64;

  uint8_t* ws = (uint8_t*)d_ws;
  size_t off = 0;
  auto carve = [&](size_t bytes) -> uint8_t* {
    uint8_t* p = ws + off;
    off += (bytes + 255) & ~(size_t)255;
    return p;
  };
  float* f0a = (float*)carve((size_t)NB * OC * 4);
  float* f0b = (float*)carve((size_t)NB * OC * 4);
  float* f1a = (float*)carve((size_t)NB * NN * OC * 4);
  float* f1b = (float*)carve((size_t)NB * NN * OC * 4);
  float* r2b = (float*)carve((size_t)NB * NN * 256 * 4);
  float* r2c = (float*)carve((size_t)NB * NN * 256 * 4);
  float* uu  = (float*)carve((size_t)NB * NN * OC * 4);
  float* vT  = (float*)carve((size_t)NB * OC * NN * 4);
  uint16_t* Wt0 = (uint16_t*)carve((size_t)OC * 128 * 2);
  uint16_t* Wt1 = (uint16_t*)carve((size_t)OC * 256 * 2);
  uint16_t* Wt2 = (uint16_t*)carve((size_t)OC * 256 * 2);
  uint16_t* Bt0 = (uint16_t*)carve((size_t)384 * 256 * 2);
  uint16_t* Bt1 = (uint16_t*)carve((size_t)384 * 512 * 2);
  uint16_t* Bt2 = (uint16_t*)carve((size_t)384 * 512 * 2);
  uint16_t* g1bf0 = (uint16_t*)carve((size_t)NB * NN * 256 * 2);
  uint16_t* g1bf1 = (uint16_t*)carve((size_t)NB * NN * 512 * 2);
  uint16_t* g1bf2 = (uint16_t*)carve((size_t)NB * NN * 512 * 2);
  __hip_bfloat16* f2a = (__hip_bfloat16*)carve(F2E * 2);

  __hip_bfloat16* f2b;
  uint16_t* x2bf;
  if (ws_size >= off + F2E * 2) {
    f2b = (__hip_bfloat16*)carve(F2E * 2);
    x2bf = (uint16_t*)f2b;  // aliases f2b; dead before f2b becomes live
  } else {
    f2b = (__hip_bfloat16*)d_in[2];  // x2 fully consumed in layer 0
    x2bf = (uint16_t*)carve(X2E * 2);
  }

  float* out_f0 = (float*)d_out;
  float* out_f1 = out_f0 + (size_t)NB * OC;
  float* out_f2 = out_f1 + (size_t)NB * NN * OC;

  prep_reduce<<<4800 + NB * NN, 256, 0, stream>>>(
      Wp[0][2], Wp[1][2], Wp[2][2], Wp[0][1], Wp[1][1], Wp[2][1], x0, x1, Wt0,
      Wt1, Wt2, Bt0, Bt1, Bt2, g1bf0, r2b, r2c, x2, x2bf);

  // ---- layer 0 (d0=32, d1=64, d2=64; KP=256) ----
  small_gemm<256, 32, 64, true><<<52, 256, 0, stream>>>(
      g1bf0, Bt0, bp[0][1], bp[0][2], f1a, g1bf1, uu, vT, x0, x1, Wp[0][0],
      bp[0][0], f0a);
  gemm2_kernel<64, __hip_bfloat16, true><<<NB * NN * 8, 256, 0, stream>>>(
      (const __hip_bfloat16*)x2bf, Wt0, uu, vT, f2a, r2b);
  conv_r2_kernel<<<NB * NN, 256, 0, stream>>>(r2b, g1bf1);

  // ---- layer 1 (all dims 128; KP=512) ----
  small_gemm<512, 128, 128, true><<<52, 256, 0, stream>>>(
      g1bf1, Bt1, bp[1][1], bp[1][2], f1b, g1bf2, uu, vT, f0a, f1a, Wp[1][0],
      bp[1][0], f0b);
  gemm2_kernel<128, __hip_bfloat16, true><<<NB * NN * 8, 256, 0, stream>>>(
      f2a, Wt1, uu, vT, f2b, r2c);
  conv_r2_kernel<<<NB * NN, 256, 0, stream>>>(r2c, g1bf2);

  // ---- layer 2 (outputs straight to d_out) ----
  small_gemm<512, 128, 128, false><<<52, 256, 0, stream>>>(
      g1bf2, Bt2, bp[2][1], bp[2][2], out_f1, nullptr, uu, vT, f0b, f1b,
      Wp[2][0], bp[2][0], out_f0);
  gemm2_kernel<128, float, false><<<NB * NN * 8, 256, 0, stream>>>(
      f2b, Wt2, uu, vT, out_f2, nullptr);
}

// Round 4
// 712.298 us; speedup vs baseline: 1.0375x; 1.0375x over previous
//
#include <hip/hip_runtime.h>
#include <hip/hip_bf16.h>
#include <cstdint>

#define NN 256
#define NB 4
#define OC 128

using bf16x8_t = __attribute__((ext_vector_type(8))) __bf16;
using f32x4_t  = __attribute__((ext_vector_type(4))) float;
using f32x16_t = __attribute__((ext_vector_type(16))) float;

typedef const __attribute__((address_space(1))) uint8_t* gptr1_t;
typedef __attribute__((address_space(3))) uint8_t* lptr3_t;

__device__ __forceinline__ void async_load16(const void* g, void* l) {
  __builtin_amdgcn_global_load_lds((gptr1_t)g, (lptr3_t)l, 16, 0, 0);
}

// sigmoid via v_rcp_f32 (1-ulp) instead of the precise-div sequence
__device__ __forceinline__ float sigf(float x) {
  return __builtin_amdgcn_rcpf(1.0f + __expf(-x));
}

__device__ __forceinline__ uint16_t f2bf_rne(float f) {
  uint32_t u = __float_as_uint(f);
  uint32_t r = (u + 0x7fffu + ((u >> 16) & 1u)) >> 16;
  return (uint16_t)r;
}

// ---- manual-pipeline primitives for gemm2 ----
// Direct global->VGPR 16B load, SGPR base + 32-bit lane byte-offset.
__device__ __forceinline__ void gload16(bf16x8_t& dst,
                                        const __hip_bfloat16* base,
                                        uint32_t voff_bytes) {
  asm volatile("global_load_dwordx4 %0, %1, %2"
               : "=v"(dst)
               : "v"(voff_bytes), "s"(base));
}
// counted-vmcnt waits + mandatory sched fence (rule #18: MFMA hoists past
// inline-asm waitcnt without it)
__device__ __forceinline__ void wvm4() {
  asm volatile("s_waitcnt vmcnt(4)" ::: "memory");
  __builtin_amdgcn_sched_barrier(0);
}
__device__ __forceinline__ void wvm2() {
  asm volatile("s_waitcnt vmcnt(2)" ::: "memory");
  __builtin_amdgcn_sched_barrier(0);
}
__device__ __forceinline__ void wvm0() {
  asm volatile("s_waitcnt vmcnt(0)" ::: "memory");
  __builtin_amdgcn_sched_barrier(0);
}

// ---------------------------------------------------------------------------
// prep (weights transpose/pack, g1bf0 static slots, r2 init)  +  reduce2 L0.
// ---------------------------------------------------------------------------
__device__ __forceinline__ void emit_wt(const float* __restrict__ W2,
                                        uint16_t* __restrict__ Wt, int d1,
                                        int d2, int idx) {
  const int K = 2 * d2;
  const int nn = idx / K, k = idx - nn * K;
  const int row = (k < d2) ? (d1 + k) : (2 * d1 + d2 + (k - d2));
  Wt[idx] = f2bf_rne(W2[row * OC + nn]);
}

__device__ __forceinline__ void emit_bt(const float* __restrict__ W1,
                                        const float* __restrict__ W2,
                                        uint16_t* __restrict__ Bt, int D0,
                                        int D1, int D2, int FIN1, int KP,
                                        int idx) {
  const int n = idx / KP, k = idx - n * KP;
  float val = 0.f;
  if (n < 128) {
    if (k < FIN1) val = W1[k * OC + n];
  } else if (n < 256) {
    if (k >= D0 && k < D0 + D1) val = W2[(k - D0) * OC + (n - 128)];
  } else {
    if (k >= D0 && k < D0 + D1) val = W2[(D1 + D2 + (k - D0)) * OC + (n - 256)];
  }
  Bt[idx] = f2bf_rne(val);
}

__global__ __launch_bounds__(256) void prep_reduce(
    const float* __restrict__ W2_0, const float* __restrict__ W2_1,
    const float* __restrict__ W2_2, const float* __restrict__ W1_0,
    const float* __restrict__ W1_1, const float* __restrict__ W1_2,
    const float* __restrict__ x0, const float* __restrict__ x1,
    uint16_t* __restrict__ Wt0, uint16_t* __restrict__ Wt1,
    uint16_t* __restrict__ Wt2, uint16_t* __restrict__ Bt0,
    uint16_t* __restrict__ Bt1, uint16_t* __restrict__ Bt2,
    uint16_t* __restrict__ g1bf0, float* __restrict__ r2b,
    float* __restrict__ r2c, const float* __restrict__ x2,
    uint16_t* __restrict__ x2bf) {
  __shared__ float4 smx[256], smn[256];
  const int blk = blockIdx.x;
  const int tid = threadIdx.x;

  if (blk < 4800) {  // ---- prep part ----
    int g = blk * 256 + tid;
    if (g < 16384) { emit_wt(W2_0, Wt0, 64, 64, g); return; }
    g -= 16384;
    if (g < 32768) { emit_wt(W2_1, Wt1, 128, 128, g); return; }
    g -= 32768;
    if (g < 32768) { emit_wt(W2_2, Wt2, 128, 128, g); return; }
    g -= 32768;
    if (g < 98304) { emit_bt(W1_0, W2_0, Bt0, 32, 64, 64, 224, 256, g); return; }
    g -= 98304;
    if (g < 196608) { emit_bt(W1_1, W2_1, Bt1, 128, 128, 128, 512, 512, g); return; }
    g -= 196608;
    if (g < 196608) { emit_bt(W1_2, W2_2, Bt2, 128, 128, 128, 512, 512, g); return; }
    g -= 196608;
    if (g < 131072) {  // g1bf0 static slots: f0[0..32) f1[32..96) pad[224..256)
      const int row = g >> 7, t = g & 127;
      uint16_t* const gp = g1bf0 + (size_t)row * 256;
      if (t < 32) gp[t] = f2bf_rne(x0[(row >> 8) * 32 + t]);
      else if (t < 96) gp[t] = f2bf_rne(x1[(size_t)row * 64 + (t - 32)]);
      else gp[128 + t] = 0;
      return;
    }
    g -= 131072;
    if (g < 262144) { r2b[g] = ((g & 255) < 128) ? 0.f : 1.f; return; }
    g -= 262144;
    if (g < 262144) { r2c[g] = ((g & 255) < 128) ? 0.f : 1.f; }
    return;
  }

  // ---- reduce2 layer 0: fp32 x2 -> bf16 x2bf + max/min into g1bf0 ----
  const int bid = blk - 4800;               // b*256 + i
  const int i = bid & 255;
  const int q = tid & 15, s = tid >> 4;
  const size_t rowbase = ((size_t)bid * NN) * 64 + q * 4;
  float mxA0 = 0.f, mxA1 = 0.f, mxA2 = 0.f, mxA3 = 0.f;
  float mnA0 = 1.f, mnA1 = 1.f, mnA2 = 1.f, mnA3 = 1.f;
  float mxB0 = 0.f, mxB1 = 0.f, mxB2 = 0.f, mxB3 = 0.f;
  float mnB0 = 1.f, mnB1 = 1.f, mnB2 = 1.f, mnB3 = 1.f;
#pragma unroll 2
  for (int t = 0; t < 16; t += 2) {
    const int jA = s + t * 16, jB = jA + 16;
    const float4 xa = *(const float4*)(x2 + rowbase + (size_t)jA * 64);
    const float4 xb = *(const float4*)(x2 + rowbase + (size_t)jB * 64);
    uint2 pa, pb;
    pa.x = (uint32_t)f2bf_rne(xa.x) | ((uint32_t)f2bf_rne(xa.y) << 16);
    pa.y = (uint32_t)f2bf_rne(xa.z) | ((uint32_t)f2bf_rne(xa.w) << 16);
    pb.x = (uint32_t)f2bf_rne(xb.x) | ((uint32_t)f2bf_rne(xb.y) << 16);
    pb.y = (uint32_t)f2bf_rne(xb.z) | ((uint32_t)f2bf_rne(xb.w) << 16);
    *(uint2*)(x2bf + rowbase + (size_t)jA * 64) = pa;
    *(uint2*)(x2bf + rowbase + (size_t)jB * 64) = pb;
    if (jA != i) {
      mxA0 = fmaxf(mxA0, xa.x); mxA1 = fmaxf(mxA1, xa.y);
      mxA2 = fmaxf(mxA2, xa.z); mxA3 = fmaxf(mxA3, xa.w);
      mnA0 = fminf(mnA0, xa.x); mnA1 = fminf(mnA1, xa.y);
      mnA2 = fminf(mnA2, xa.z); mnA3 = fminf(mnA3, xa.w);
    }
    if (jB != i) {
      mxB0 = fmaxf(mxB0, xb.x); mxB1 = fmaxf(mxB1, xb.y);
      mxB2 = fmaxf(mxB2, xb.z); mxB3 = fmaxf(mxB3, xb.w);
      mnB0 = fminf(mnB0, xb.x); mnB1 = fminf(mnB1, xb.y);
      mnB2 = fminf(mnB2, xb.z); mnB3 = fminf(mnB3, xb.w);
    }
  }
  float mx0 = fmaxf(mxA0, mxB0), mx1 = fmaxf(mxA1, mxB1);
  float mx2 = fmaxf(mxA2, mxB2), mx3 = fmaxf(mxA3, mxB3);
  float mn0 = fminf(mnA0, mnB0), mn1 = fminf(mnA1, mnB1);
  float mn2 = fminf(mnA2, mnB2), mn3 = fminf(mnA3, mnB3);
  smx[tid] = make_float4(mx0, mx1, mx2, mx3);
  smn[tid] = make_float4(mn0, mn1, mn2, mn3);
  __syncthreads();
  if (s == 0) {
    for (int ss = 1; ss < 16; ++ss) {
      float4 a = smx[q + ss * 16], c = smn[q + ss * 16];
      mx0 = fmaxf(mx0, a.x); mx1 = fmaxf(mx1, a.y);
      mx2 = fmaxf(mx2, a.z); mx3 = fmaxf(mx3, a.w);
      mn0 = fminf(mn0, c.x); mn1 = fminf(mn1, c.y);
      mn2 = fminf(mn2, c.z); mn3 = fminf(mn3, c.w);
    }
    uint16_t* const g = g1bf0 + (size_t)bid * 256;
    g[96 + q * 4 + 0] = f2bf_rne(mx0); g[96 + q * 4 + 1] = f2bf_rne(mx1);
    g[96 + q * 4 + 2] = f2bf_rne(mx2); g[96 + q * 4 + 3] = f2bf_rne(mx3);
    g[160 + q * 4 + 0] = f2bf_rne(mn0); g[160 + q * 4 + 1] = f2bf_rne(mn1);
    g[160 + q * 4 + 2] = f2bf_rne(mn2); g[160 + q * 4 + 3] = f2bf_rne(mn3);
  }
}

// ---------------------------------------------------------------------------
// Small fused MFMA GEMM + o0 (round-0 proven LDS-staged structure).
// ---------------------------------------------------------------------------
template <int KP, int D0, int D1, bool DUP>
__global__ __launch_bounds__(256) void small_gemm(
    const uint16_t* __restrict__ g1, const uint16_t* __restrict__ Bt,
    const float* __restrict__ b1, const float* __restrict__ b2,
    float* __restrict__ f1out, uint16_t* __restrict__ g1next,
    float* __restrict__ u, float* __restrict__ vT,
    const float* __restrict__ f0in, const float* __restrict__ f1in,
    const float* __restrict__ W0, const float* __restrict__ b0,
    float* __restrict__ f0out) {
  constexpr int NCH = KP / 64;
  const int bid = blockIdx.x;
  const int tid = threadIdx.x;

  __shared__ __align__(16) uint8_t ldsA[8192];
  __shared__ __align__(16) uint8_t ldsB[16384];

  if (bid < 48) {
    const int mt = bid / 3, nt = bid - mt * 3;
    const int m0 = mt * 64, n0 = nt * 128;
    const int wv = tid >> 6, lane = tid & 63;
    const int l15 = lane & 15, l4 = lane >> 4;

    f32x4_t acc[4][2];
#pragma unroll
    for (int a = 0; a < 4; ++a)
#pragma unroll
      for (int q = 0; q < 2; ++q) acc[a][q] = (f32x4_t){0.f, 0.f, 0.f, 0.f};

    for (int c = 0; c < NCH; ++c) {
      const int kbg = c * 64;
#pragma unroll
      for (int t = 0; t < 2; ++t) {  // A units: id = ks*4 + mi
        const int id = wv * 2 + t;
        const int mi = id & 3, ks = id >> 2;
        async_load16(g1 + (size_t)(m0 + mi * 16 + l15) * KP + kbg + ks * 32 + l4 * 8,
                     ldsA + id * 1024);
      }
#pragma unroll
      for (int t = 0; t < 4; ++t) {  // B units: id = ks*8 + ni
        const int id = wv * 4 + t;
        const int ni = id & 7, ks = id >> 3;
        async_load16(Bt + (size_t)(n0 + ni * 16 + l15) * KP + kbg + ks * 32 + l4 * 8,
                     ldsB + id * 1024);
      }
      __syncthreads();
#pragma unroll
      for (int ks = 0; ks < 2; ++ks) {
        bf16x8_t Af[4], Bf[2];
#pragma unroll
        for (int a = 0; a < 4; ++a)
          Af[a] = *(const bf16x8_t*)(ldsA + ((ks * 4 + a) << 10) + (lane << 4));
#pragma unroll
        for (int q = 0; q < 2; ++q)
          Bf[q] = *(const bf16x8_t*)(ldsB + ((ks * 8 + wv * 2 + q) << 10) + (lane << 4));
#pragma unroll
        for (int a = 0; a < 4; ++a)
#pragma unroll
          for (int q = 0; q < 2; ++q)
            acc[a][q] = __builtin_amdgcn_mfma_f32_16x16x32_bf16(Af[a], Bf[q],
                                                                acc[a][q], 0, 0, 0);
      }
      __syncthreads();
    }

    float bias[2];
#pragma unroll
    for (int q = 0; q < 2; ++q) {
      const int cc = wv * 32 + q * 16 + l15;
      bias[q] = (nt == 0) ? b1[cc] : ((nt == 1) ? b2[cc] : 0.f);
    }
#pragma unroll
    for (int a = 0; a < 4; ++a) {
      const int rl = a * 16 + l4 * 4;
#pragma unroll
      for (int r = 0; r < 4; ++r) {
        const size_t bi = m0 + rl + r;
#pragma unroll
        for (int q = 0; q < 2; ++q) {
          const int cc = wv * 32 + q * 16 + l15;
          const float x = acc[a][q][r] + bias[q];
          if (nt == 0) {
            const float val = sigf(x);
            f1out[bi * OC + cc] = val;
            if (DUP) g1next[bi * 512 + 128 + cc] = f2bf_rne(val);
          } else if (nt == 1) {
            u[bi * OC + cc] = x;
          } else {
            const int b = (int)(bi >> 8), j = (int)(bi & 255);
            vT[((size_t)b * OC + cc) * NN + j] = x;
          }
        }
      }
    }
  } else {
    // ---- o0 for batch b ----
    constexpr int FIN0 = D0 + 2 * D1;
    constexpr int S = 256 / D1;
    const int b = bid - 48;
    float* const sm = (float*)ldsA;   // reuse LDS: g0 | smx | smn | sval
    float* const g0 = sm;
    float* const smx = sm + 512;
    float* const smn = sm + 768;
    float* const sval = sm + 1024;
    const int cc = tid & (D1 - 1), ss = tid / D1;
    float mx = -1e30f, mn = 1e30f;
    const float* f1b = f1in + (size_t)b * NN * D1;
    for (int j = ss; j < NN; j += S) {
      const float x = f1b[(size_t)j * D1 + cc];
      mx = fmaxf(mx, x); mn = fminf(mn, x);
    }
    smx[tid] = mx; smn[tid] = mn;
    __syncthreads();
    if (ss == 0) {
      for (int s2 = 1; s2 < S; ++s2) {
        mx = fmaxf(mx, smx[cc + s2 * D1]);
        mn = fminf(mn, smn[cc + s2 * D1]);
      }
      g0[D0 + cc] = mx;
      g0[D0 + D1 + cc] = mn;
    }
    if (tid < D0) g0[tid] = f0in[b * D0 + tid];
    __syncthreads();
    if (tid < OC) {
      float acc = b0[tid];
#pragma unroll 8
      for (int k = 0; k < FIN0; ++k) acc += g0[k] * W0[k * OC + tid];
      const float val = sigf(acc);
      f0out[b * OC + tid] = val;
      sval[tid] = val;
    }
    if (DUP) {
      __syncthreads();
      for (int idx = tid; idx < 256 * 128; idx += 256) {
        const int row = idx >> 7, c2 = idx & 127;
        g1next[((size_t)(b * 256 + row)) * 512 + c2] = f2bf_rne(sval[c2]);
      }
    }
  }
}

// ---------------------------------------------------------------------------
// conv: fp32 r2 (post gemm2 atomics) -> bf16 into g1next r2 slot [256..512).
// ---------------------------------------------------------------------------
__global__ __launch_bounds__(256) void conv_r2_kernel(
    const float* __restrict__ r2, uint16_t* __restrict__ g1next) {
  const int bi = blockIdx.x, t = threadIdx.x;
  g1next[(size_t)bi * 512 + 256 + t] = f2bf_rne(r2[(size_t)bi * 256 + t]);
}

// ---------------------------------------------------------------------------
// Big order-2 GEMM, v4: 32x32 tile/wave (acc 16 VGPR), 8-waves/SIMD occupancy
// band, and a HAND-BUILT software pipeline: inline-asm global_load_dwordx4
// into a 4-slot rotating register buffer, 3 (A,W) pairs in flight, counted
// s_waitcnt vmcnt(4)->2->0 + sched_barrier fences (round-3 post-mortem:
// under the 64-VGPR cap the compiler emits a serial load->wait->MFMA chain;
// asm forces the AITER-style MFMA<->load interleave).
// C/D layout (m74/m101): col = lane&31, row = (reg&3)+8*(reg>>2)+4*(lane>>5).
// ---------------------------------------------------------------------------
template <int D2, typename OUT_T, bool REDUCE>
__global__ __launch_bounds__(256, 8) void gemm2_kernel(
    const __hip_bfloat16* __restrict__ f2, const uint16_t* __restrict__ Wt,
    const float* __restrict__ u, const float* __restrict__ vT,
    OUT_T* __restrict__ out, float* __restrict__ r2n) {
  constexpr int K = 2 * D2;
  constexpr int NST = K / 16;
  constexpr bool BF16OUT = (sizeof(OUT_T) == 2);

  const int bid = blockIdx.x;
  const int strip = bid & 7, i = (bid >> 3) & 255, b = bid >> 11;
  const int j0 = strip * 32;
  const int tid = threadIdx.x;
  const int wv = tid >> 6, lane = tid & 63;
  const int l31 = lane & 31, hi = lane >> 5;
  const int c0 = wv * 32;

  __shared__ unsigned smax[128], smin[128];

  const __hip_bfloat16* const A1 = f2 + ((size_t)(b * NN + i) * NN + j0) * D2;
  const __hip_bfloat16* const A2 = f2 + ((size_t)(b * NN + j0) * NN + i) * D2;
  const __hip_bfloat16* const Wg = (const __hip_bfloat16*)Wt;

  // per-lane BYTE offsets (uniform SGPR base walks the K dimension)
  const uint32_t voffA1 = ((uint32_t)l31 * D2 + hi * 8) * 2;
  const uint32_t voffA2 = ((uint32_t)l31 * (NN * D2) + hi * 8) * 2;
  const uint32_t voffW  = ((uint32_t)(c0 + l31) * K + hi * 8) * 2;

  f32x16_t acc = {0.f, 0.f, 0.f, 0.f, 0.f, 0.f, 0.f, 0.f,
                  0.f, 0.f, 0.f, 0.f, 0.f, 0.f, 0.f, 0.f};
  bf16x8_t Ab[4], Wb[4];

  // prologue: pairs 0,1,2 in flight (6 loads)
#pragma unroll
  for (int s = 0; s < 3; ++s) {
    const int kb = s * 16;
    if (kb < D2) gload16(Ab[s], A1 + kb, voffA1);
    else         gload16(Ab[s], A2 + (kb - D2), voffA2);
    gload16(Wb[s], Wg + kb, voffW);
  }

#pragma unroll
  for (int s = 0; s < NST; ++s) {
    // drain pair s (4 newer loads may stay in flight), tail: 2 -> 0
    if (NST - 1 - s >= 2) wvm4();
    else if (NST - 1 - s == 1) wvm2();
    else wvm0();
    if (s + 3 < NST) {  // issue pair s+3 into the slot freed at step s-1
      const int kb = (s + 3) * 16;
      if (kb < D2) gload16(Ab[(s + 3) & 3], A1 + kb, voffA1);
      else         gload16(Ab[(s + 3) & 3], A2 + (kb - D2), voffA2);
      gload16(Wb[(s + 3) & 3], Wg + kb, voffW);
    }
    acc = __builtin_amdgcn_mfma_f32_32x32x16_bf16(Ab[s & 3], Wb[s & 3], acc,
                                                  0, 0, 0);
  }

  const size_t bi2 = (size_t)(b * NN + i);
  const int col = c0 + l31;
  const float uv = u[bi2 * OC + col];
  const float* const vTc = vT + ((size_t)b * OC + col) * NN + j0;  // 32 j's
  const size_t obase = (bi2 * NN + j0) * OC + col;

  if (BF16OUT) {
    if (REDUCE) {
      if (tid < 128) { smax[tid] = 0u; smin[tid] = 0x3f800000u; }
      __syncthreads();
    }
    float lmx = 0.f, lmn = 1.f;
    uint16_t* const outp = (uint16_t*)out;
#pragma unroll
    for (int rg = 0; rg < 4; ++rg) {
      const int rbase = rg * 8 + 4 * hi;  // row base within strip
      const float4 vq = *(const float4*)(vTc + rbase);
#pragma unroll
      for (int rr = 0; rr < 4; ++rr) {
        const int row = rbase + rr;
        const float x = acc[rg * 4 + rr] + uv + ((const float*)&vq)[rr];
        const float sg = sigf(x);
        outp[obase + (size_t)row * OC] = f2bf_rne(sg);
        if (REDUCE && (j0 + row) != i) {
          lmx = fmaxf(lmx, sg);
          lmn = fminf(lmn, sg);
        }
      }
    }
    if (REDUCE) {
      atomicMax(&smax[col], __float_as_uint(lmx));
      atomicMin(&smin[col], __float_as_uint(lmn));
      __syncthreads();
      if (tid < 128) {
        unsigned* const r2u = (unsigned*)r2n;
        atomicMax(&r2u[bi2 * 256 + tid], smax[tid]);
        atomicMin(&r2u[bi2 * 256 + 128 + tid], smin[tid]);
      }
    }
  } else {
    float* const outp = (float*)out;
#pragma unroll
    for (int rg = 0; rg < 4; ++rg) {
      const int rbase = rg * 8 + 4 * hi;
      const float4 vq = *(const float4*)(vTc + rbase);
#pragma unroll
      for (int rr = 0; rr < 4; ++rr) {
        const int row = rbase + rr;
        const float x = acc[rg * 4 + rr] + uv + ((const float*)&vq)[rr];
        outp[obase + (size_t)row * OC] = sigf(x);
      }
    }
  }
}

// ---------------------------------------------------------------------------
extern "C" void kernel_launch(void* const* d_in, const int* in_sizes, int n_in,
                              void* d_out, int out_size, void* d_ws,
                              size_t ws_size, hipStream_t stream) {
  const float* x0 = (const float*)d_in[0];
  const float* x1 = (const float*)d_in[1];
  const float* x2 = (const float*)d_in[2];
  const float *Wp[3][3], *bp[3][3];
  for (int l = 0; l < 3; ++l)
    for (int o = 0; o < 3; ++o) {
      Wp[l][o] = (const float*)d_in[3 + l * 6 + o * 2];
      bp[l][o] = (const float*)d_in[3 + l * 6 + o * 2 + 1];
    }

  const size_t F2E = (size_t)NB * NN * NN * OC;
  const size_t X2E = (size_t)NB * NN * NN * 64;

  uint8_t* ws = (uint8_t*)d_ws;
  size_t off = 0;
  auto carve = [&](size_t bytes) -> uint8_t* {
    uint8_t* p = ws + off;
    off += (bytes + 255) & ~(size_t)255;
    return p;
  };
  float* f0a = (float*)carve((size_t)NB * OC * 4);
  float* f0b = (float*)carve((size_t)NB * OC * 4);
  float* f1a = (float*)carve((size_t)NB * NN * OC * 4);
  float* f1b = (float*)carve((size_t)NB * NN * OC * 4);
  float* r2b = (float*)carve((size_t)NB * NN * 256 * 4);
  float* r2c = (float*)carve((size_t)NB * NN * 256 * 4);
  float* uu  = (float*)carve((size_t)NB * NN * OC * 4);
  float* vT  = (float*)carve((size_t)NB * OC * NN * 4);
  uint16_t* Wt0 = (uint16_t*)carve((size_t)OC * 128 * 2);
  uint16_t* Wt1 = (uint16_t*)carve((size_t)OC * 256 * 2);
  uint16_t* Wt2 = (uint16_t*)carve((size_t)OC * 256 * 2);
  uint16_t* Bt0 = (uint16_t*)carve((size_t)384 * 256 * 2);
  uint16_t* Bt1 = (uint16_t*)carve((size_t)384 * 512 * 2);
  uint16_t* Bt2 = (uint16_t*)carve((size_t)384 * 512 * 2);
  uint16_t* g1bf0 = (uint16_t*)carve((size_t)NB * NN * 256 * 2);
  uint16_t* g1bf1 = (uint16_t*)carve((size_t)NB * NN * 512 * 2);
  uint16_t* g1bf2 = (uint16_t*)carve((size_t)NB * NN * 512 * 2);
  __hip_bfloat16* f2a = (__hip_bfloat16*)carve(F2E * 2);

  __hip_bfloat16* f2b;
  uint16_t* x2bf;
  if (ws_size >= off + F2E * 2) {
    f2b = (__hip_bfloat16*)carve(F2E * 2);
    x2bf = (uint16_t*)f2b;  // aliases f2b; dead before f2b becomes live
  } else {
    f2b = (__hip_bfloat16*)d_in[2];  // x2 fully consumed in layer 0
    x2bf = (uint16_t*)carve(X2E * 2);
  }

  float* out_f0 = (float*)d_out;
  float* out_f1 = out_f0 + (size_t)NB * OC;
  float* out_f2 = out_f1 + (size_t)NB * NN * OC;

  prep_reduce<<<4800 + NB * NN, 256, 0, stream>>>(
      Wp[0][2], Wp[1][2], Wp[2][2], Wp[0][1], Wp[1][1], Wp[2][1], x0, x1, Wt0,
      Wt1, Wt2, Bt0, Bt1, Bt2, g1bf0, r2b, r2c, x2, x2bf);

  // ---- layer 0 (d0=32, d1=64, d2=64; KP=256) ----
  small_gemm<256, 32, 64, true><<<52, 256, 0, stream>>>(
      g1bf0, Bt0, bp[0][1], bp[0][2], f1a, g1bf1, uu, vT, x0, x1, Wp[0][0],
      bp[0][0], f0a);
  gemm2_kernel<64, __hip_bfloat16, true><<<NB * NN * 8, 256, 0, stream>>>(
      (const __hip_bfloat16*)x2bf, Wt0, uu, vT, f2a, r2b);
  conv_r2_kernel<<<NB * NN, 256, 0, stream>>>(r2b, g1bf1);

  // ---- layer 1 (all dims 128; KP=512) ----
  small_gemm<512, 128, 128, true><<<52, 256, 0, stream>>>(
      g1bf1, Bt1, bp[1][1], bp[1][2], f1b, g1bf2, uu, vT, f0a, f1a, Wp[1][0],
      bp[1][0], f0b);
  gemm2_kernel<128, __hip_bfloat16, true><<<NB * NN * 8, 256, 0, stream>>>(
      f2a, Wt1, uu, vT, f2b, r2c);
  conv_r2_kernel<<<NB * NN, 256, 0, stream>>>(r2c, g1bf2);

  // ---- layer 2 (outputs straight to d_out) ----
  small_gemm<512, 128, 128, false><<<52, 256, 0, stream>>>(
      g1bf2, Bt2, bp[2][1], bp[2][2], out_f1, nullptr, uu, vT, f0b, f1b,
      Wp[2][0], bp[2][0], out_f0);
  gemm2_kernel<128, float, false><<<NB * NN * 8, 256, 0, stream>>>(
      f2b, Wt2, uu, vT, out_f2, nullptr);
}

// Round 5
// 550.219 us; speedup vs baseline: 1.3432x; 1.2946x over previous
//
#include <hip/hip_runtime.h>
#include <hip/hip_bf16.h>
#include <cstdint>

#define NN 256
#define NB 4
#define OC 128

using bf16x8_t = __attribute__((ext_vector_type(8))) __bf16;
using f32x4_t  = __attribute__((ext_vector_type(4))) float;

typedef const __attribute__((address_space(1))) uint8_t* gptr1_t;
typedef __attribute__((address_space(3))) uint8_t* lptr3_t;

__device__ __forceinline__ void async_load16(const void* g, void* l) {
  __builtin_amdgcn_global_load_lds((gptr1_t)g, (lptr3_t)l, 16, 0, 0);
}

template <int N>
__device__ __forceinline__ void wvmN() {
  asm volatile("s_waitcnt vmcnt(%0)" ::"n"(N) : "memory");
  __builtin_amdgcn_sched_barrier(0);
}

// sigmoid via v_rcp_f32 (1-ulp) instead of the precise-div sequence
__device__ __forceinline__ float sigf(float x) {
  return __builtin_amdgcn_rcpf(1.0f + __expf(-x));
}

__device__ __forceinline__ uint16_t f2bf_rne(float f) {
  uint32_t u = __float_as_uint(f);
  uint32_t r = (u + 0x7fffu + ((u >> 16) & 1u)) >> 16;
  return (uint16_t)r;
}

// ---------------------------------------------------------------------------
// prep (weights transpose/pack, g1bf0 static slots, r2 init)  +  reduce2 L0.
// ---------------------------------------------------------------------------
__device__ __forceinline__ void emit_wt(const float* __restrict__ W2,
                                        uint16_t* __restrict__ Wt, int d1,
                                        int d2, int idx) {
  const int K = 2 * d2;
  const int nn = idx / K, k = idx - nn * K;
  const int row = (k < d2) ? (d1 + k) : (2 * d1 + d2 + (k - d2));
  Wt[idx] = f2bf_rne(W2[row * OC + nn]);
}

__device__ __forceinline__ void emit_bt(const float* __restrict__ W1,
                                        const float* __restrict__ W2,
                                        uint16_t* __restrict__ Bt, int D0,
                                        int D1, int D2, int FIN1, int KP,
                                        int idx) {
  const int n = idx / KP, k = idx - n * KP;
  float val = 0.f;
  if (n < 128) {
    if (k < FIN1) val = W1[k * OC + n];
  } else if (n < 256) {
    if (k >= D0 && k < D0 + D1) val = W2[(k - D0) * OC + (n - 128)];
  } else {
    if (k >= D0 && k < D0 + D1) val = W2[(D1 + D2 + (k - D0)) * OC + (n - 256)];
  }
  Bt[idx] = f2bf_rne(val);
}

__global__ __launch_bounds__(256) void prep_reduce(
    const float* __restrict__ W2_0, const float* __restrict__ W2_1,
    const float* __restrict__ W2_2, const float* __restrict__ W1_0,
    const float* __restrict__ W1_1, const float* __restrict__ W1_2,
    const float* __restrict__ x0, const float* __restrict__ x1,
    uint16_t* __restrict__ Wt0, uint16_t* __restrict__ Wt1,
    uint16_t* __restrict__ Wt2, uint16_t* __restrict__ Bt0,
    uint16_t* __restrict__ Bt1, uint16_t* __restrict__ Bt2,
    uint16_t* __restrict__ g1bf0, float* __restrict__ r2b,
    float* __restrict__ r2c, const float* __restrict__ x2,
    uint16_t* __restrict__ x2bf) {
  __shared__ float4 smx[256], smn[256];
  const int blk = blockIdx.x;
  const int tid = threadIdx.x;

  if (blk < 4800) {  // ---- prep part ----
    int g = blk * 256 + tid;
    if (g < 16384) { emit_wt(W2_0, Wt0, 64, 64, g); return; }
    g -= 16384;
    if (g < 32768) { emit_wt(W2_1, Wt1, 128, 128, g); return; }
    g -= 32768;
    if (g < 32768) { emit_wt(W2_2, Wt2, 128, 128, g); return; }
    g -= 32768;
    if (g < 98304) { emit_bt(W1_0, W2_0, Bt0, 32, 64, 64, 224, 256, g); return; }
    g -= 98304;
    if (g < 196608) { emit_bt(W1_1, W2_1, Bt1, 128, 128, 128, 512, 512, g); return; }
    g -= 196608;
    if (g < 196608) { emit_bt(W1_2, W2_2, Bt2, 128, 128, 128, 512, 512, g); return; }
    g -= 196608;
    if (g < 131072) {  // g1bf0 static slots: f0[0..32) f1[32..96) pad[224..256)
      const int row = g >> 7, t = g & 127;
      uint16_t* const gp = g1bf0 + (size_t)row * 256;
      if (t < 32) gp[t] = f2bf_rne(x0[(row >> 8) * 32 + t]);
      else if (t < 96) gp[t] = f2bf_rne(x1[(size_t)row * 64 + (t - 32)]);
      else gp[128 + t] = 0;
      return;
    }
    g -= 131072;
    if (g < 262144) { r2b[g] = ((g & 255) < 128) ? 0.f : 1.f; return; }
    g -= 262144;
    if (g < 262144) { r2c[g] = ((g & 255) < 128) ? 0.f : 1.f; }
    return;
  }

  // ---- reduce2 layer 0: fp32 x2 -> bf16 x2bf + max/min into g1bf0 ----
  const int bid = blk - 4800;               // b*256 + i
  const int i = bid & 255;
  const int q = tid & 15, s = tid >> 4;
  const size_t rowbase = ((size_t)bid * NN) * 64 + q * 4;
  float mxA0 = 0.f, mxA1 = 0.f, mxA2 = 0.f, mxA3 = 0.f;
  float mnA0 = 1.f, mnA1 = 1.f, mnA2 = 1.f, mnA3 = 1.f;
  float mxB0 = 0.f, mxB1 = 0.f, mxB2 = 0.f, mxB3 = 0.f;
  float mnB0 = 1.f, mnB1 = 1.f, mnB2 = 1.f, mnB3 = 1.f;
#pragma unroll 2
  for (int t = 0; t < 16; t += 2) {
    const int jA = s + t * 16, jB = jA + 16;
    const float4 xa = *(const float4*)(x2 + rowbase + (size_t)jA * 64);
    const float4 xb = *(const float4*)(x2 + rowbase + (size_t)jB * 64);
    uint2 pa, pb;
    pa.x = (uint32_t)f2bf_rne(xa.x) | ((uint32_t)f2bf_rne(xa.y) << 16);
    pa.y = (uint32_t)f2bf_rne(xa.z) | ((uint32_t)f2bf_rne(xa.w) << 16);
    pb.x = (uint32_t)f2bf_rne(xb.x) | ((uint32_t)f2bf_rne(xb.y) << 16);
    pb.y = (uint32_t)f2bf_rne(xb.z) | ((uint32_t)f2bf_rne(xb.w) << 16);
    *(uint2*)(x2bf + rowbase + (size_t)jA * 64) = pa;
    *(uint2*)(x2bf + rowbase + (size_t)jB * 64) = pb;
    if (jA != i) {
      mxA0 = fmaxf(mxA0, xa.x); mxA1 = fmaxf(mxA1, xa.y);
      mxA2 = fmaxf(mxA2, xa.z); mxA3 = fmaxf(mxA3, xa.w);
      mnA0 = fminf(mnA0, xa.x); mnA1 = fminf(mnA1, xa.y);
      mnA2 = fminf(mnA2, xa.z); mnA3 = fminf(mnA3, xa.w);
    }
    if (jB != i) {
      mxB0 = fmaxf(mxB0, xb.x); mxB1 = fmaxf(mxB1, xb.y);
      mxB2 = fmaxf(mxB2, xb.z); mxB3 = fmaxf(mxB3, xb.w);
      mnB0 = fminf(mnB0, xb.x); mnB1 = fminf(mnB1, xb.y);
      mnB2 = fminf(mnB2, xb.z); mnB3 = fminf(mnB3, xb.w);
    }
  }
  float mx0 = fmaxf(mxA0, mxB0), mx1 = fmaxf(mxA1, mxB1);
  float mx2 = fmaxf(mxA2, mxB2), mx3 = fmaxf(mxA3, mxB3);
  float mn0 = fminf(mnA0, mnB0), mn1 = fminf(mnA1, mnB1);
  float mn2 = fminf(mnA2, mnB2), mn3 = fminf(mnA3, mnB3);
  smx[tid] = make_float4(mx0, mx1, mx2, mx3);
  smn[tid] = make_float4(mn0, mn1, mn2, mn3);
  __syncthreads();
  if (s == 0) {
    for (int ss = 1; ss < 16; ++ss) {
      float4 a = smx[q + ss * 16], c = smn[q + ss * 16];
      mx0 = fmaxf(mx0, a.x); mx1 = fmaxf(mx1, a.y);
      mx2 = fmaxf(mx2, a.z); mx3 = fmaxf(mx3, a.w);
      mn0 = fminf(mn0, c.x); mn1 = fminf(mn1, c.y);
      mn2 = fminf(mn2, c.z); mn3 = fminf(mn3, c.w);
    }
    uint16_t* const g = g1bf0 + (size_t)bid * 256;
    g[96 + q * 4 + 0] = f2bf_rne(mx0); g[96 + q * 4 + 1] = f2bf_rne(mx1);
    g[96 + q * 4 + 2] = f2bf_rne(mx2); g[96 + q * 4 + 3] = f2bf_rne(mx3);
    g[160 + q * 4 + 0] = f2bf_rne(mn0); g[160 + q * 4 + 1] = f2bf_rne(mn1);
    g[160 + q * 4 + 2] = f2bf_rne(mn2); g[160 + q * 4 + 3] = f2bf_rne(mn3);
  }
}

// ---------------------------------------------------------------------------
// Small fused MFMA GEMM + o0 (round-0 proven LDS-staged structure).
// ---------------------------------------------------------------------------
template <int KP, int D0, int D1, bool DUP>
__global__ __launch_bounds__(256) void small_gemm(
    const uint16_t* __restrict__ g1, const uint16_t* __restrict__ Bt,
    const float* __restrict__ b1, const float* __restrict__ b2,
    float* __restrict__ f1out, uint16_t* __restrict__ g1next,
    float* __restrict__ u, float* __restrict__ vT,
    const float* __restrict__ f0in, const float* __restrict__ f1in,
    const float* __restrict__ W0, const float* __restrict__ b0,
    float* __restrict__ f0out) {
  constexpr int NCH = KP / 64;
  const int bid = blockIdx.x;
  const int tid = threadIdx.x;

  __shared__ __align__(16) uint8_t ldsA[8192];
  __shared__ __align__(16) uint8_t ldsB[16384];

  if (bid < 48) {
    const int mt = bid / 3, nt = bid - mt * 3;
    const int m0 = mt * 64, n0 = nt * 128;
    const int wv = tid >> 6, lane = tid & 63;
    const int l15 = lane & 15, l4 = lane >> 4;

    f32x4_t acc[4][2];
#pragma unroll
    for (int a = 0; a < 4; ++a)
#pragma unroll
      for (int q = 0; q < 2; ++q) acc[a][q] = (f32x4_t){0.f, 0.f, 0.f, 0.f};

    for (int c = 0; c < NCH; ++c) {
      const int kbg = c * 64;
#pragma unroll
      for (int t = 0; t < 2; ++t) {  // A units: id = ks*4 + mi
        const int id = wv * 2 + t;
        const int mi = id & 3, ks = id >> 2;
        async_load16(g1 + (size_t)(m0 + mi * 16 + l15) * KP + kbg + ks * 32 + l4 * 8,
                     ldsA + id * 1024);
      }
#pragma unroll
      for (int t = 0; t < 4; ++t) {  // B units: id = ks*8 + ni
        const int id = wv * 4 + t;
        const int ni = id & 7, ks = id >> 3;
        async_load16(Bt + (size_t)(n0 + ni * 16 + l15) * KP + kbg + ks * 32 + l4 * 8,
                     ldsB + id * 1024);
      }
      __syncthreads();
#pragma unroll
      for (int ks = 0; ks < 2; ++ks) {
        bf16x8_t Af[4], Bf[2];
#pragma unroll
        for (int a = 0; a < 4; ++a)
          Af[a] = *(const bf16x8_t*)(ldsA + ((ks * 4 + a) << 10) + (lane << 4));
#pragma unroll
        for (int q = 0; q < 2; ++q)
          Bf[q] = *(const bf16x8_t*)(ldsB + ((ks * 8 + wv * 2 + q) << 10) + (lane << 4));
#pragma unroll
        for (int a = 0; a < 4; ++a)
#pragma unroll
          for (int q = 0; q < 2; ++q)
            acc[a][q] = __builtin_amdgcn_mfma_f32_16x16x32_bf16(Af[a], Bf[q],
                                                                acc[a][q], 0, 0, 0);
      }
      __syncthreads();
    }

    float bias[2];
#pragma unroll
    for (int q = 0; q < 2; ++q) {
      const int cc = wv * 32 + q * 16 + l15;
      bias[q] = (nt == 0) ? b1[cc] : ((nt == 1) ? b2[cc] : 0.f);
    }
#pragma unroll
    for (int a = 0; a < 4; ++a) {
      const int rl = a * 16 + l4 * 4;
#pragma unroll
      for (int r = 0; r < 4; ++r) {
        const size_t bi = m0 + rl + r;
#pragma unroll
        for (int q = 0; q < 2; ++q) {
          const int cc = wv * 32 + q * 16 + l15;
          const float x = acc[a][q][r] + bias[q];
          if (nt == 0) {
            const float val = sigf(x);
            f1out[bi * OC + cc] = val;
            if (DUP) g1next[bi * 512 + 128 + cc] = f2bf_rne(val);
          } else if (nt == 1) {
            u[bi * OC + cc] = x;
          } else {
            const int b = (int)(bi >> 8), j = (int)(bi & 255);
            vT[((size_t)b * OC + cc) * NN + j] = x;
          }
        }
      }
    }
  } else {
    // ---- o0 for batch b ----
    constexpr int FIN0 = D0 + 2 * D1;
    constexpr int S = 256 / D1;
    const int b = bid - 48;
    float* const sm = (float*)ldsA;   // reuse LDS: g0 | smx | smn | sval
    float* const g0 = sm;
    float* const smx = sm + 512;
    float* const smn = sm + 768;
    float* const sval = sm + 1024;
    const int cc = tid & (D1 - 1), ss = tid / D1;
    float mx = -1e30f, mn = 1e30f;
    const float* f1b = f1in + (size_t)b * NN * D1;
    for (int j = ss; j < NN; j += S) {
      const float x = f1b[(size_t)j * D1 + cc];
      mx = fmaxf(mx, x); mn = fminf(mn, x);
    }
    smx[tid] = mx; smn[tid] = mn;
    __syncthreads();
    if (ss == 0) {
      for (int s2 = 1; s2 < S; ++s2) {
        mx = fmaxf(mx, smx[cc + s2 * D1]);
        mn = fminf(mn, smn[cc + s2 * D1]);
      }
      g0[D0 + cc] = mx;
      g0[D0 + D1 + cc] = mn;
    }
    if (tid < D0) g0[tid] = f0in[b * D0 + tid];
    __syncthreads();
    if (tid < OC) {
      float acc = b0[tid];
#pragma unroll 8
      for (int k = 0; k < FIN0; ++k) acc += g0[k] * W0[k * OC + tid];
      const float val = sigf(acc);
      f0out[b * OC + tid] = val;
      sval[tid] = val;
    }
    if (DUP) {
      __syncthreads();
      for (int idx = tid; idx < 256 * 128; idx += 256) {
        const int row = idx >> 7, c2 = idx & 127;
        g1next[((size_t)(b * 256 + row)) * 512 + c2] = f2bf_rne(sval[c2]);
      }
    }
  }
}

// ---------------------------------------------------------------------------
// conv: fp32 r2 (post gemm2 atomics) -> bf16 into g1next r2 slot [256..512).
// ---------------------------------------------------------------------------
__global__ __launch_bounds__(256) void conv_r2_kernel(
    const float* __restrict__ r2, uint16_t* __restrict__ g1next) {
  const int bi = blockIdx.x, t = threadIdx.x;
  g1next[(size_t)bi * 512 + 256 + t] = f2bf_rne(r2[(size_t)bi * 256 + t]);
}

// ---------------------------------------------------------------------------
// Big order-2 GEMM, v5: BULK-PREFETCH streaming. The ENTIRE A tile (128xK)
// and W tile (128xK) are issued as global_load_lds DMA up front (NCH*4 insts
// per wave = up to 32 KB in flight per wave, no VGPR cost), then chunks are
// consumed with a DESCENDING counted vmcnt (28,24,...,0) + one s_barrier per
// chunk. Buffers are write-once: no double-buffering, no re-staging, NCH
// barriers total. Regime: memory-parallelism-limited streaming; this gives
// ~30x the outstanding bytes of the 4-loads-per-chunk pipeline.
// LDS: [A: NCH*8K][W: NCH*8K]; epilogue staging aliases the A region.
// l1/l2: 128 KB -> 1 block/CU. l0: 64 KB -> 2 blocks/CU.
// ---------------------------------------------------------------------------
template <int D2, typename OUT_T, bool REDUCE>
__global__ __launch_bounds__(256) void gemm2_kernel(
    const __hip_bfloat16* __restrict__ f2, const uint16_t* __restrict__ Wt,
    const float* __restrict__ u, const float* __restrict__ vT,
    OUT_T* __restrict__ out, float* __restrict__ r2n) {
  constexpr int K = 2 * D2;
  constexpr int NCH = K / 32;
  constexpr int ABYTES = 128 * K * 2;  // 32 KB (l0) or 64 KB (l1/l2)
  const int bid = blockIdx.x;
  // pair-preserving bijective XCD swizzle: 1024 (b,i) pairs, 128 per XCD
  const int jt = bid & 1;
  const int pair = bid >> 1;
  const int sp = (pair & 7) * 128 + (pair >> 3);
  const int i = sp & 255, b = sp >> 8;
  const int j0 = jt * 128;
  const int tid = threadIdx.x;
  const int wv = tid >> 6, lane = tid & 63;
  const int wr = wv >> 1, wc = wv & 1;
  const int l15 = lane & 15, l4 = lane >> 4;

  __shared__ __align__(16) uint8_t lds[2 * ABYTES];
  __shared__ unsigned smax[128], smin[128];

  const __hip_bfloat16* const A1 = f2 + ((size_t)(b * NN + i) * NN + j0) * D2;
  const __hip_bfloat16* const A2 = f2 + ((size_t)(b * NN + j0) * NN + i) * D2;

  f32x4_t acc[4][4];
#pragma unroll
  for (int a = 0; a < 4; ++a)
#pragma unroll
    for (int q = 0; q < 4; ++q) acc[a][q] = (f32x4_t){0.f, 0.f, 0.f, 0.f};

  // ---- bulk prefetch: all NCH chunks, chunk-major, 4 insts/wave/chunk ----
#pragma unroll
  for (int c = 0; c < NCH; ++c) {
    const int kbg = c * 32;
    const bool second = (kbg >= D2);
    const __hip_bfloat16* const Ab = second ? A2 : A1;
    const size_t rstr = second ? (size_t)NN * D2 : (size_t)D2;
    const int kbase = second ? (kbg - D2) : kbg;
#pragma unroll
    for (int t = 0; t < 2; ++t) {
      const int mi = wv * 2 + t;  // row-block 0..7
      async_load16(Ab + (size_t)(mi * 16 + l15) * rstr + kbase + l4 * 8,
                   lds + c * 8192 + mi * 1024);
    }
#pragma unroll
    for (int t = 0; t < 2; ++t) {
      const int ni = wv * 2 + t;  // col-block 0..7
      async_load16(Wt + (size_t)(ni * 16 + l15) * K + kbg + l4 * 8,
                   lds + ABYTES + c * 8192 + ni * 1024);
    }
  }

  auto compute_chunk = [&](int c) {
    const uint8_t* const bA = lds + c * 8192;
    const uint8_t* const bW = lds + ABYTES + c * 8192;
    bf16x8_t Af[4], Bf[4];
#pragma unroll
    for (int a = 0; a < 4; ++a)
      Af[a] = *(const bf16x8_t*)(bA + ((wr * 4 + a) << 10) + (lane << 4));
#pragma unroll
    for (int q = 0; q < 4; ++q)
      Bf[q] = *(const bf16x8_t*)(bW + ((wc * 4 + q) << 10) + (lane << 4));
#pragma unroll
    for (int a = 0; a < 4; ++a)
#pragma unroll
      for (int q = 0; q < 4; ++q)
        acc[a][q] = __builtin_amdgcn_mfma_f32_16x16x32_bf16(Af[a], Bf[q],
                                                            acc[a][q], 0, 0, 0);
  };

#define G2_STEP(c)                                                     \
  if constexpr ((c) < NCH) {                                           \
    wvmN<(NCH - 1 - (c)) * 4>();                                       \
    __builtin_amdgcn_s_barrier();                                      \
    __builtin_amdgcn_sched_barrier(0);                                 \
    compute_chunk(c);                                                  \
  }
  G2_STEP(0) G2_STEP(1) G2_STEP(2) G2_STEP(3)
  G2_STEP(4) G2_STEP(5) G2_STEP(6) G2_STEP(7)
#undef G2_STEP

  __syncthreads();  // all LDS reads done before epilogue aliases region

  const size_t bi2 = (size_t)(b * NN + i);
  float uval[4];
#pragma unroll
  for (int q = 0; q < 4; ++q) uval[q] = u[bi2 * OC + wc * 64 + q * 16 + l15];
  const size_t obase = (bi2 * NN + j0) * OC;
  const float* const vTb = vT + (size_t)b * OC * NN;
  constexpr bool BF16OUT = (sizeof(OUT_T) == 2);

  if (BF16OUT) {
    if (REDUCE && tid < 128) { smax[tid] = 0u; smin[tid] = 0x3f800000u; }
    __syncthreads();
    float lmx[4] = {0.f, 0.f, 0.f, 0.f};
    float lmn[4] = {1.f, 1.f, 1.f, 1.f};
#pragma unroll
    for (int a = 0; a < 4; ++a) {
      const int rowb = wr * 64 + a * 16 + l4 * 4;
      const int jg = j0 + rowb;
#pragma unroll
      for (int q = 0; q < 4; ++q) {
        const int col = wc * 64 + q * 16 + l15;
        const float4 vq = *(const float4*)(vTb + (size_t)col * NN + jg);
#pragma unroll
        for (int r = 0; r < 4; ++r) {
          const int j = rowb + r;
          const float x = acc[a][q][r] + uval[q] + ((const float*)&vq)[r];
          const float sg = sigf(x);
          *(uint16_t*)(lds + j * 272 + col * 2) = f2bf_rne(sg);
          if (REDUCE && (jg + r) != i) {
            lmx[q] = fmaxf(lmx[q], sg);
            lmn[q] = fminf(lmn[q], sg);
          }
        }
      }
    }
    if (REDUCE) {
#pragma unroll
      for (int q = 0; q < 4; ++q) {
        const int col = wc * 64 + q * 16 + l15;
        atomicMax(&smax[col], __float_as_uint(lmx[q]));
        atomicMin(&smin[col], __float_as_uint(lmn[q]));
      }
    }
    __syncthreads();
    uint16_t* const outp = (uint16_t*)out;
#pragma unroll
    for (int ci = 0; ci < 8; ++ci) {
      const int chunk = ci * 256 + tid;
      const int row = chunk >> 4, off = chunk & 15;
      const uint4 val = *(const uint4*)(lds + row * 272 + off * 16);
      *(uint4*)(outp + obase + (size_t)row * OC + off * 8) = val;
    }
    if (REDUCE && tid < 128) {
      unsigned* const r2u = (unsigned*)r2n;
      atomicMax(&r2u[bi2 * 256 + tid], smax[tid]);
      atomicMin(&r2u[bi2 * 256 + 128 + tid], smin[tid]);
    }
  } else {
    float* const outp = (float*)out;
#pragma unroll
    for (int a = 0; a < 4; ++a) {
      const int rowb = wr * 64 + a * 16 + l4 * 4;
      const int jg = j0 + rowb;
#pragma unroll
      for (int q = 0; q < 4; ++q) {
        const int col = wc * 64 + q * 16 + l15;
        const float4 vq = *(const float4*)(vTb + (size_t)col * NN + jg);
#pragma unroll
        for (int r = 0; r < 4; ++r) {
          const int j = rowb + r;
          const float x = acc[a][q][r] + uval[q] + ((const float*)&vq)[r];
          outp[obase + (size_t)j * OC + col] = sigf(x);
        }
      }
    }
  }
}

// ---------------------------------------------------------------------------
extern "C" void kernel_launch(void* const* d_in, const int* in_sizes, int n_in,
                              void* d_out, int out_size, void* d_ws,
                              size_t ws_size, hipStream_t stream) {
  const float* x0 = (const float*)d_in[0];
  const float* x1 = (const float*)d_in[1];
  const float* x2 = (const float*)d_in[2];
  const float *Wp[3][3], *bp[3][3];
  for (int l = 0; l < 3; ++l)
    for (int o = 0; o < 3; ++o) {
      Wp[l][o] = (const float*)d_in[3 + l * 6 + o * 2];
      bp[l][o] = (const float*)d_in[3 + l * 6 + o * 2 + 1];
    }

  const size_t F2E = (size_t)NB * NN * NN * OC;
  const size_t X2E = (size_t)NB * NN * NN * 64;

  uint8_t* ws = (uint8_t*)d_ws;
  size_t off = 0;
  auto carve = [&](size_t bytes) -> uint8_t* {
    uint8_t* p = ws + off;
    off += (bytes + 255) & ~(size_t)255;
    return p;
  };
  float* f0a = (float*)carve((size_t)NB * OC * 4);
  float* f0b = (float*)carve((size_t)NB * OC * 4);
  float* f1a = (float*)carve((size_t)NB * NN * OC * 4);
  float* f1b = (float*)carve((size_t)NB * NN * OC * 4);
  float* r2b = (float*)carve((size_t)NB * NN * 256 * 4);
  float* r2c = (float*)carve((size_t)NB * NN * 256 * 4);
  float* uu  = (float*)carve((size_t)NB * NN * OC * 4);
  float* vT  = (float*)carve((size_t)NB * OC * NN * 4);
  uint16_t* Wt0 = (uint16_t*)carve((size_t)OC * 128 * 2);
  uint16_t* Wt1 = (uint16_t*)carve((size_t)OC * 256 * 2);
  uint16_t* Wt2 = (uint16_t*)carve((size_t)OC * 256 * 2);
  uint16_t* Bt0 = (uint16_t*)carve((size_t)384 * 256 * 2);
  uint16_t* Bt1 = (uint16_t*)carve((size_t)384 * 512 * 2);
  uint16_t* Bt2 = (uint16_t*)carve((size_t)384 * 512 * 2);
  uint16_t* g1bf0 = (uint16_t*)carve((size_t)NB * NN * 256 * 2);
  uint16_t* g1bf1 = (uint16_t*)carve((size_t)NB * NN * 512 * 2);
  uint16_t* g1bf2 = (uint16_t*)carve((size_t)NB * NN * 512 * 2);
  __hip_bfloat16* f2a = (__hip_bfloat16*)carve(F2E * 2);

  __hip_bfloat16* f2b;
  uint16_t* x2bf;
  if (ws_size >= off + F2E * 2) {
    f2b = (__hip_bfloat16*)carve(F2E * 2);
    x2bf = (uint16_t*)f2b;  // aliases f2b; dead before f2b becomes live
  } else {
    f2b = (__hip_bfloat16*)d_in[2];  // x2 fully consumed in layer 0
    x2bf = (uint16_t*)carve(X2E * 2);
  }

  float* out_f0 = (float*)d_out;
  float* out_f1 = out_f0 + (size_t)NB * OC;
  float* out_f2 = out_f1 + (size_t)NB * NN * OC;

  prep_reduce<<<4800 + NB * NN, 256, 0, stream>>>(
      Wp[0][2], Wp[1][2], Wp[2][2], Wp[0][1], Wp[1][1], Wp[2][1], x0, x1, Wt0,
      Wt1, Wt2, Bt0, Bt1, Bt2, g1bf0, r2b, r2c, x2, x2bf);

  // ---- layer 0 (d0=32, d1=64, d2=64; KP=256) ----
  small_gemm<256, 32, 64, true><<<52, 256, 0, stream>>>(
      g1bf0, Bt0, bp[0][1], bp[0][2], f1a, g1bf1, uu, vT, x0, x1, Wp[0][0],
      bp[0][0], f0a);
  gemm2_kernel<64, __hip_bfloat16, true><<<NB * NN * 2, 256, 0, stream>>>(
      (const __hip_bfloat16*)x2bf, Wt0, uu, vT, f2a, r2b);
  conv_r2_kernel<<<NB * NN, 256, 0, stream>>>(r2b, g1bf1);

  // ---- layer 1 (all dims 128; KP=512) ----
  small_gemm<512, 128, 128, true><<<52, 256, 0, stream>>>(
      g1bf1, Bt1, bp[1][1], bp[1][2], f1b, g1bf2, uu, vT, f0a, f1a, Wp[1][0],
      bp[1][0], f0b);
  gemm2_kernel<128, __hip_bfloat16, true><<<NB * NN * 2, 256, 0, stream>>>(
      f2a, Wt1, uu, vT, f2b, r2c);
  conv_r2_kernel<<<NB * NN, 256, 0, stream>>>(r2c, g1bf2);

  // ---- layer 2 (outputs straight to d_out) ----
  small_gemm<512, 128, 128, false><<<52, 256, 0, stream>>>(
      g1bf2, Bt2, bp[2][1], bp[2][2], out_f1, nullptr, uu, vT, f0b, f1b,
      Wp[2][0], bp[2][0], out_f0);
  gemm2_kernel<128, float, false><<<NB * NN * 2, 256, 0, stream>>>(
      f2b, Wt2, uu, vT, out_f2, nullptr);
}

// Round 6
// 526.025 us; speedup vs baseline: 1.4049x; 1.0460x over previous
//
#include <hip/hip_runtime.h>
#include <hip/hip_bf16.h>
#include <cstdint>

#define NN 256
#define NB 4
#define OC 128

using bf16x8_t = __attribute__((ext_vector_type(8))) __bf16;
using f32x4_t  = __attribute__((ext_vector_type(4))) float;

typedef const __attribute__((address_space(1))) uint8_t* gptr1_t;
typedef __attribute__((address_space(3))) uint8_t* lptr3_t;

__device__ __forceinline__ void async_load16(const void* g, void* l) {
  __builtin_amdgcn_global_load_lds((gptr1_t)g, (lptr3_t)l, 16, 0, 0);
}

// sigmoid via v_rcp_f32 (1-ulp) instead of the precise-div sequence
__device__ __forceinline__ float sigf(float x) {
  return __builtin_amdgcn_rcpf(1.0f + __expf(-x));
}

__device__ __forceinline__ uint16_t f2bf_rne(float f) {
  uint32_t u = __float_as_uint(f);
  uint32_t r = (u + 0x7fffu + ((u >> 16) & 1u)) >> 16;
  return (uint16_t)r;
}

// ---------------------------------------------------------------------------
// prep (weights transpose/pack, g1bf0 static slots, r2 init)  +  reduce2 L0.
// ---------------------------------------------------------------------------
__device__ __forceinline__ void emit_wt(const float* __restrict__ W2,
                                        uint16_t* __restrict__ Wt, int d1,
                                        int d2, int idx) {
  const int K = 2 * d2;
  const int nn = idx / K, k = idx - nn * K;
  const int row = (k < d2) ? (d1 + k) : (2 * d1 + d2 + (k - d2));
  Wt[idx] = f2bf_rne(W2[row * OC + nn]);
}

__device__ __forceinline__ void emit_bt(const float* __restrict__ W1,
                                        const float* __restrict__ W2,
                                        uint16_t* __restrict__ Bt, int D0,
                                        int D1, int D2, int FIN1, int KP,
                                        int idx) {
  const int n = idx / KP, k = idx - n * KP;
  float val = 0.f;
  if (n < 128) {
    if (k < FIN1) val = W1[k * OC + n];
  } else if (n < 256) {
    if (k >= D0 && k < D0 + D1) val = W2[(k - D0) * OC + (n - 128)];
  } else {
    if (k >= D0 && k < D0 + D1) val = W2[(D1 + D2 + (k - D0)) * OC + (n - 256)];
  }
  Bt[idx] = f2bf_rne(val);
}

__global__ __launch_bounds__(256) void prep_reduce(
    const float* __restrict__ W2_0, const float* __restrict__ W2_1,
    const float* __restrict__ W2_2, const float* __restrict__ W1_0,
    const float* __restrict__ W1_1, const float* __restrict__ W1_2,
    const float* __restrict__ x0, const float* __restrict__ x1,
    uint16_t* __restrict__ Wt0, uint16_t* __restrict__ Wt1,
    uint16_t* __restrict__ Wt2, uint16_t* __restrict__ Bt0,
    uint16_t* __restrict__ Bt1, uint16_t* __restrict__ Bt2,
    uint16_t* __restrict__ g1bf0, float* __restrict__ r2b,
    float* __restrict__ r2c, const float* __restrict__ x2,
    uint16_t* __restrict__ x2bf) {
  __shared__ float4 smx[256], smn[256];
  const int blk = blockIdx.x;
  const int tid = threadIdx.x;

  if (blk < 4800) {  // ---- prep part ----
    int g = blk * 256 + tid;
    if (g < 16384) { emit_wt(W2_0, Wt0, 64, 64, g); return; }
    g -= 16384;
    if (g < 32768) { emit_wt(W2_1, Wt1, 128, 128, g); return; }
    g -= 32768;
    if (g < 32768) { emit_wt(W2_2, Wt2, 128, 128, g); return; }
    g -= 32768;
    if (g < 98304) { emit_bt(W1_0, W2_0, Bt0, 32, 64, 64, 224, 256, g); return; }
    g -= 98304;
    if (g < 196608) { emit_bt(W1_1, W2_1, Bt1, 128, 128, 128, 512, 512, g); return; }
    g -= 196608;
    if (g < 196608) { emit_bt(W1_2, W2_2, Bt2, 128, 128, 128, 512, 512, g); return; }
    g -= 196608;
    if (g < 131072) {  // g1bf0 static slots: f0[0..32) f1[32..96) pad[224..256)
      const int row = g >> 7, t = g & 127;
      uint16_t* const gp = g1bf0 + (size_t)row * 256;
      if (t < 32) gp[t] = f2bf_rne(x0[(row >> 8) * 32 + t]);
      else if (t < 96) gp[t] = f2bf_rne(x1[(size_t)row * 64 + (t - 32)]);
      else gp[128 + t] = 0;
      return;
    }
    g -= 131072;
    if (g < 262144) { r2b[g] = ((g & 255) < 128) ? 0.f : 1.f; return; }
    g -= 262144;
    if (g < 262144) { r2c[g] = ((g & 255) < 128) ? 0.f : 1.f; }
    return;
  }

  // ---- reduce2 layer 0: fp32 x2 -> bf16 x2bf + max/min into g1bf0 ----
  const int bid = blk - 4800;               // b*256 + i
  const int i = bid & 255;
  const int q = tid & 15, s = tid >> 4;
  const size_t rowbase = ((size_t)bid * NN) * 64 + q * 4;
  float mxA0 = 0.f, mxA1 = 0.f, mxA2 = 0.f, mxA3 = 0.f;
  float mnA0 = 1.f, mnA1 = 1.f, mnA2 = 1.f, mnA3 = 1.f;
  float mxB0 = 0.f, mxB1 = 0.f, mxB2 = 0.f, mxB3 = 0.f;
  float mnB0 = 1.f, mnB1 = 1.f, mnB2 = 1.f, mnB3 = 1.f;
#pragma unroll 2
  for (int t = 0; t < 16; t += 2) {
    const int jA = s + t * 16, jB = jA + 16;
    const float4 xa = *(const float4*)(x2 + rowbase + (size_t)jA * 64);
    const float4 xb = *(const float4*)(x2 + rowbase + (size_t)jB * 64);
    uint2 pa, pb;
    pa.x = (uint32_t)f2bf_rne(xa.x) | ((uint32_t)f2bf_rne(xa.y) << 16);
    pa.y = (uint32_t)f2bf_rne(xa.z) | ((uint32_t)f2bf_rne(xa.w) << 16);
    pb.x = (uint32_t)f2bf_rne(xb.x) | ((uint32_t)f2bf_rne(xb.y) << 16);
    pb.y = (uint32_t)f2bf_rne(xb.z) | ((uint32_t)f2bf_rne(xb.w) << 16);
    *(uint2*)(x2bf + rowbase + (size_t)jA * 64) = pa;
    *(uint2*)(x2bf + rowbase + (size_t)jB * 64) = pb;
    if (jA != i) {
      mxA0 = fmaxf(mxA0, xa.x); mxA1 = fmaxf(mxA1, xa.y);
      mxA2 = fmaxf(mxA2, xa.z); mxA3 = fmaxf(mxA3, xa.w);
      mnA0 = fminf(mnA0, xa.x); mnA1 = fminf(mnA1, xa.y);
      mnA2 = fminf(mnA2, xa.z); mnA3 = fminf(mnA3, xa.w);
    }
    if (jB != i) {
      mxB0 = fmaxf(mxB0, xb.x); mxB1 = fmaxf(mxB1, xb.y);
      mxB2 = fmaxf(mxB2, xb.z); mxB3 = fmaxf(mxB3, xb.w);
      mnB0 = fminf(mnB0, xb.x); mnB1 = fminf(mnB1, xb.y);
      mnB2 = fminf(mnB2, xb.z); mnB3 = fminf(mnB3, xb.w);
    }
  }
  float mx0 = fmaxf(mxA0, mxB0), mx1 = fmaxf(mxA1, mxB1);
  float mx2 = fmaxf(mxA2, mxB2), mx3 = fmaxf(mxA3, mxB3);
  float mn0 = fminf(mnA0, mnB0), mn1 = fminf(mnA1, mnB1);
  float mn2 = fminf(mnA2, mnB2), mn3 = fminf(mnA3, mnB3);
  smx[tid] = make_float4(mx0, mx1, mx2, mx3);
  smn[tid] = make_float4(mn0, mn1, mn2, mn3);
  __syncthreads();
  if (s == 0) {
    for (int ss = 1; ss < 16; ++ss) {
      float4 a = smx[q + ss * 16], c = smn[q + ss * 16];
      mx0 = fmaxf(mx0, a.x); mx1 = fmaxf(mx1, a.y);
      mx2 = fmaxf(mx2, a.z); mx3 = fmaxf(mx3, a.w);
      mn0 = fminf(mn0, c.x); mn1 = fminf(mn1, c.y);
      mn2 = fminf(mn2, c.z); mn3 = fminf(mn3, c.w);
    }
    uint16_t* const g = g1bf0 + (size_t)bid * 256;
    g[96 + q * 4 + 0] = f2bf_rne(mx0); g[96 + q * 4 + 1] = f2bf_rne(mx1);
    g[96 + q * 4 + 2] = f2bf_rne(mx2); g[96 + q * 4 + 3] = f2bf_rne(mx3);
    g[160 + q * 4 + 0] = f2bf_rne(mn0); g[160 + q * 4 + 1] = f2bf_rne(mn1);
    g[160 + q * 4 + 2] = f2bf_rne(mn2); g[160 + q * 4 + 3] = f2bf_rne(mn3);
  }
}

// ---------------------------------------------------------------------------
// Small fused MFMA GEMM + o0 (round-0 proven LDS-staged structure).
// ---------------------------------------------------------------------------
template <int KP, int D0, int D1, bool DUP>
__global__ __launch_bounds__(256) void small_gemm(
    const uint16_t* __restrict__ g1, const uint16_t* __restrict__ Bt,
    const float* __restrict__ b1, const float* __restrict__ b2,
    float* __restrict__ f1out, uint16_t* __restrict__ g1next,
    float* __restrict__ u, float* __restrict__ vT,
    const float* __restrict__ f0in, const float* __restrict__ f1in,
    const float* __restrict__ W0, const float* __restrict__ b0,
    float* __restrict__ f0out) {
  constexpr int NCH = KP / 64;
  const int bid = blockIdx.x;
  const int tid = threadIdx.x;

  __shared__ __align__(16) uint8_t ldsA[8192];
  __shared__ __align__(16) uint8_t ldsB[16384];

  if (bid < 48) {
    const int mt = bid / 3, nt = bid - mt * 3;
    const int m0 = mt * 64, n0 = nt * 128;
    const int wv = tid >> 6, lane = tid & 63;
    const int l15 = lane & 15, l4 = lane >> 4;

    f32x4_t acc[4][2];
#pragma unroll
    for (int a = 0; a < 4; ++a)
#pragma unroll
      for (int q = 0; q < 2; ++q) acc[a][q] = (f32x4_t){0.f, 0.f, 0.f, 0.f};

    for (int c = 0; c < NCH; ++c) {
      const int kbg = c * 64;
#pragma unroll
      for (int t = 0; t < 2; ++t) {  // A units: id = ks*4 + mi
        const int id = wv * 2 + t;
        const int mi = id & 3, ks = id >> 2;
        async_load16(g1 + (size_t)(m0 + mi * 16 + l15) * KP + kbg + ks * 32 + l4 * 8,
                     ldsA + id * 1024);
      }
#pragma unroll
      for (int t = 0; t < 4; ++t) {  // B units: id = ks*8 + ni
        const int id = wv * 4 + t;
        const int ni = id & 7, ks = id >> 3;
        async_load16(Bt + (size_t)(n0 + ni * 16 + l15) * KP + kbg + ks * 32 + l4 * 8,
                     ldsB + id * 1024);
      }
      __syncthreads();
#pragma unroll
      for (int ks = 0; ks < 2; ++ks) {
        bf16x8_t Af[4], Bf[2];
#pragma unroll
        for (int a = 0; a < 4; ++a)
          Af[a] = *(const bf16x8_t*)(ldsA + ((ks * 4 + a) << 10) + (lane << 4));
#pragma unroll
        for (int q = 0; q < 2; ++q)
          Bf[q] = *(const bf16x8_t*)(ldsB + ((ks * 8 + wv * 2 + q) << 10) + (lane << 4));
#pragma unroll
        for (int a = 0; a < 4; ++a)
#pragma unroll
          for (int q = 0; q < 2; ++q)
            acc[a][q] = __builtin_amdgcn_mfma_f32_16x16x32_bf16(Af[a], Bf[q],
                                                                acc[a][q], 0, 0, 0);
      }
      __syncthreads();
    }

    float bias[2];
#pragma unroll
    for (int q = 0; q < 2; ++q) {
      const int cc = wv * 32 + q * 16 + l15;
      bias[q] = (nt == 0) ? b1[cc] : ((nt == 1) ? b2[cc] : 0.f);
    }
#pragma unroll
    for (int a = 0; a < 4; ++a) {
      const int rl = a * 16 + l4 * 4;
#pragma unroll
      for (int r = 0; r < 4; ++r) {
        const size_t bi = m0 + rl + r;
#pragma unroll
        for (int q = 0; q < 2; ++q) {
          const int cc = wv * 32 + q * 16 + l15;
          const float x = acc[a][q][r] + bias[q];
          if (nt == 0) {
            const float val = sigf(x);
            f1out[bi * OC + cc] = val;
            if (DUP) g1next[bi * 512 + 128 + cc] = f2bf_rne(val);
          } else if (nt == 1) {
            u[bi * OC + cc] = x;
          } else {
            const int b = (int)(bi >> 8), j = (int)(bi & 255);
            vT[((size_t)b * OC + cc) * NN + j] = x;
          }
        }
      }
    }
  } else {
    // ---- o0 for batch b ----
    constexpr int FIN0 = D0 + 2 * D1;
    constexpr int S = 256 / D1;
    const int b = bid - 48;
    float* const sm = (float*)ldsA;   // reuse LDS: g0 | smx | smn | sval
    float* const g0 = sm;
    float* const smx = sm + 512;
    float* const smn = sm + 768;
    float* const sval = sm + 1024;
    const int cc = tid & (D1 - 1), ss = tid / D1;
    float mx = -1e30f, mn = 1e30f;
    const float* f1b = f1in + (size_t)b * NN * D1;
    for (int j = ss; j < NN; j += S) {
      const float x = f1b[(size_t)j * D1 + cc];
      mx = fmaxf(mx, x); mn = fminf(mn, x);
    }
    smx[tid] = mx; smn[tid] = mn;
    __syncthreads();
    if (ss == 0) {
      for (int s2 = 1; s2 < S; ++s2) {
        mx = fmaxf(mx, smx[cc + s2 * D1]);
        mn = fminf(mn, smn[cc + s2 * D1]);
      }
      g0[D0 + cc] = mx;
      g0[D0 + D1 + cc] = mn;
    }
    if (tid < D0) g0[tid] = f0in[b * D0 + tid];
    __syncthreads();
    if (tid < OC) {
      float acc = b0[tid];
#pragma unroll 8
      for (int k = 0; k < FIN0; ++k) acc += g0[k] * W0[k * OC + tid];
      const float val = sigf(acc);
      f0out[b * OC + tid] = val;
      sval[tid] = val;
    }
    if (DUP) {
      __syncthreads();
      for (int idx = tid; idx < 256 * 128; idx += 256) {
        const int row = idx >> 7, c2 = idx & 127;
        g1next[((size_t)(b * 256 + row)) * 512 + c2] = f2bf_rne(sval[c2]);
      }
    }
  }
}

// ---------------------------------------------------------------------------
// conv: fp32 r2 (post gemm2 atomics) -> bf16 into g1next r2 slot [256..512).
// ---------------------------------------------------------------------------
__global__ __launch_bounds__(256) void conv_r2_kernel(
    const float* __restrict__ r2, uint16_t* __restrict__ g1next) {
  const int bi = blockIdx.x, t = threadIdx.x;
  g1next[(size_t)bi * 512 + 256 + t] = f2bf_rne(r2[(size_t)bi * 256 + t]);
}

// ---------------------------------------------------------------------------
// Big order-2 GEMM, v6: TRANSACTION-EFFICIENT staging. Theory (R0-R5 data):
// every prior variant staged with consecutive lanes strided by the row pitch
// (16B granules on 16-64 distinct cache lines per wave-instruction), pinning
// the TA/L2 request rate at the same ~83us regardless of depth/occupancy.
// Fix: stage whole K-major ROWS so each wave-instruction reads a CONTIGUOUS
// 1KB window (consecutive lanes = adjacent 16B -> ~4x fewer transactions).
// LDS becomes [row][K] row-major (a 16-way bank-conflict layout), fixed with
// the rule-21 pair: pre-swizzled SOURCE (pos ^ ((row&7)<<4), within-row so
// within-instruction) + identical XOR on the ds_read side.
// Layout: [W: 128 x K][A1: 128 x D2][A2: 128 x D2]; 2-phase consumption
// (K-half1 from A1, K-half2 from A2) with counted vmcnt at phase 1 so the
// A2 DMA stays in flight. 2 barriers per block. Epilogue unchanged (aliases
// the W region after the K-loop).
// ---------------------------------------------------------------------------
template <int D2, typename OUT_T, bool REDUCE>
__global__ __launch_bounds__(256) void gemm2_kernel(
    const __hip_bfloat16* __restrict__ f2, const uint16_t* __restrict__ Wt,
    const float* __restrict__ u, const float* __restrict__ vT,
    OUT_T* __restrict__ out, float* __restrict__ r2n) {
  constexpr int K = 2 * D2;
  constexpr int NST = K / 32;          // 16x16x32 k-slices (4 or 8)
  constexpr int AROW = D2 * 2;         // A row bytes (128 or 256)
  constexpr int WROW = K * 2;          // W row bytes (256 or 512)
  constexpr int ABYTES = 128 * AROW;   // 16 KB or 32 KB
  constexpr int WBYTES = 128 * WROW;   // 32 KB or 64 KB
  constexpr int NIW = WBYTES / 4096;   // W insts/wave (8 or 16)
  constexpr int NIA = ABYTES / 4096;   // A-half insts/wave (4 or 8)
  constexpr bool BF16OUT = (sizeof(OUT_T) == 2);

  const int bid = blockIdx.x;
  // pair-preserving bijective XCD swizzle: 1024 (b,i) pairs, 128 per XCD
  const int jt = bid & 1;
  const int pair = bid >> 1;
  const int sp = (pair & 7) * 128 + (pair >> 3);
  const int i = sp & 255, b = sp >> 8;
  const int j0 = jt * 128;
  const int tid = threadIdx.x;
  const int wv = tid >> 6, lane = tid & 63;
  const int wr = wv >> 1, wc = wv & 1;
  const int l15 = lane & 15, l4 = lane >> 4;

  __shared__ __align__(16) uint8_t lds[WBYTES + 2 * ABYTES];
  __shared__ unsigned smax[128], smin[128];
  uint8_t* const ldsW = lds;
  uint8_t* const ldsA1 = lds + WBYTES;
  uint8_t* const ldsA2 = lds + WBYTES + ABYTES;

  const uint8_t* const A1g =
      (const uint8_t*)(f2 + ((size_t)(b * NN + i) * NN + j0) * D2);
  const uint8_t* const A2g =
      (const uint8_t*)(f2 + ((size_t)(b * NN + j0) * NN + i) * D2);
  const uint8_t* const Wg = (const uint8_t*)Wt;

  // ---- stage W: contiguous 1KB windows, row-swizzled source ----
  {
    constexpr int LPR = WROW / 16;     // lanes per row (16 or 32)
    constexpr int WPR = 64 / LPR;      // rows per window (4 or 2)
#pragma unroll
    for (int t = 0; t < NIW; ++t) {
      const int id = wv * NIW + t;
      const int grow = id * WPR + lane / LPR;
      const int pos = (lane % LPR) * 16;
      async_load16(Wg + (size_t)grow * WROW + (pos ^ ((grow & 7) << 4)),
                   ldsW + id * 1024 + lane * 16);
    }
  }
  // ---- stage A1 (fully contiguous region) and A2 (row stride NN*D2) ----
  {
    constexpr int LPR = AROW / 16;     // 8 or 16
    constexpr int WPR = 64 / LPR;      // 8 or 4
#pragma unroll
    for (int t = 0; t < NIA; ++t) {
      const int id = wv * NIA + t;
      const int grow = id * WPR + lane / LPR;
      const int pos = (lane % LPR) * 16;
      async_load16(A1g + (size_t)grow * AROW + (pos ^ ((grow & 7) << 4)),
                   ldsA1 + id * 1024 + lane * 16);
    }
#pragma unroll
    for (int t = 0; t < NIA; ++t) {
      const int id = wv * NIA + t;
      const int grow = id * WPR + lane / LPR;
      const int pos = (lane % LPR) * 16;
      async_load16(A2g + (size_t)grow * (NN * D2 * 2) + (pos ^ ((grow & 7) << 4)),
                   ldsA2 + id * 1024 + lane * 16);
    }
  }

  f32x4_t acc[4][4];
#pragma unroll
  for (int a = 0; a < 4; ++a)
#pragma unroll
    for (int q = 0; q < 4; ++q) acc[a][q] = (f32x4_t){0.f, 0.f, 0.f, 0.f};

  auto do_phase = [&](const uint8_t* bA, int h) {
#pragma unroll
    for (int ksl = 0; ksl < NST / 2; ++ksl) {
      const int ks = h * (NST / 2) + ksl;
      bf16x8_t Af[4], Bf[4];
#pragma unroll
      for (int a = 0; a < 4; ++a) {
        const int row = (wr * 4 + a) * 16 + l15;
        Af[a] = *(const bf16x8_t*)(bA + row * AROW +
                                   ((ksl * 64 + l4 * 16) ^ ((row & 7) << 4)));
      }
#pragma unroll
      for (int q = 0; q < 4; ++q) {
        const int n = wc * 64 + q * 16 + l15;
        Bf[q] = *(const bf16x8_t*)(ldsW + n * WROW +
                                   ((ks * 64 + l4 * 16) ^ ((n & 7) << 4)));
      }
#pragma unroll
      for (int a = 0; a < 4; ++a)
#pragma unroll
        for (int q = 0; q < 4; ++q)
          acc[a][q] = __builtin_amdgcn_mfma_f32_16x16x32_bf16(Af[a], Bf[q],
                                                              acc[a][q], 0, 0, 0);
    }
  };

  // phase 1: W + A1 landed (A2's NIA loads still in flight)
  asm volatile("s_waitcnt vmcnt(%0)" ::"n"(NIA) : "memory");
  __builtin_amdgcn_sched_barrier(0);
  __builtin_amdgcn_s_barrier();
  __builtin_amdgcn_sched_barrier(0);
  do_phase(ldsA1, 0);
  // phase 2: A2 landed
  asm volatile("s_waitcnt vmcnt(0)" ::: "memory");
  __builtin_amdgcn_sched_barrier(0);
  __builtin_amdgcn_s_barrier();
  __builtin_amdgcn_sched_barrier(0);
  do_phase(ldsA2, 1);

  __syncthreads();  // all LDS reads done before epilogue aliases W region

  const size_t bi2 = (size_t)(b * NN + i);
  float uval[4];
#pragma unroll
  for (int q = 0; q < 4; ++q) uval[q] = u[bi2 * OC + wc * 64 + q * 16 + l15];
  const size_t obase = (bi2 * NN + j0) * OC;
  const float* const vTb = vT + (size_t)b * OC * NN;

  if (BF16OUT) {
    if (REDUCE && tid < 128) { smax[tid] = 0u; smin[tid] = 0x3f800000u; }
    __syncthreads();
    float lmx[4] = {0.f, 0.f, 0.f, 0.f};
    float lmn[4] = {1.f, 1.f, 1.f, 1.f};
#pragma unroll
    for (int a = 0; a < 4; ++a) {
      const int rowb = wr * 64 + a * 16 + l4 * 4;
      const int jg = j0 + rowb;
#pragma unroll
      for (int q = 0; q < 4; ++q) {
        const int col = wc * 64 + q * 16 + l15;
        const float4 vq = *(const float4*)(vTb + (size_t)col * NN + jg);
#pragma unroll
        for (int r = 0; r < 4; ++r) {
          const int j = rowb + r;
          const float x = acc[a][q][r] + uval[q] + ((const float*)&vq)[r];
          const float sg = sigf(x);
          *(uint16_t*)(lds + j * 272 + col * 2) = f2bf_rne(sg);
          if (REDUCE && (jg + r) != i) {
            lmx[q] = fmaxf(lmx[q], sg);
            lmn[q] = fminf(lmn[q], sg);
          }
        }
      }
    }
    if (REDUCE) {
#pragma unroll
      for (int q = 0; q < 4; ++q) {
        const int col = wc * 64 + q * 16 + l15;
        atomicMax(&smax[col], __float_as_uint(lmx[q]));
        atomicMin(&smin[col], __float_as_uint(lmn[q]));
      }
    }
    __syncthreads();
    uint16_t* const outp = (uint16_t*)out;
#pragma unroll
    for (int ci = 0; ci < 8; ++ci) {
      const int chunk = ci * 256 + tid;
      const int row = chunk >> 4, off = chunk & 15;
      const uint4 val = *(const uint4*)(lds + row * 272 + off * 16);
      *(uint4*)(outp + obase + (size_t)row * OC + off * 8) = val;
    }
    if (REDUCE && tid < 128) {
      unsigned* const r2u = (unsigned*)r2n;
      atomicMax(&r2u[bi2 * 256 + tid], smax[tid]);
      atomicMin(&r2u[bi2 * 256 + 128 + tid], smin[tid]);
    }
  } else {
    float* const outp = (float*)out;
#pragma unroll
    for (int a = 0; a < 4; ++a) {
      const int rowb = wr * 64 + a * 16 + l4 * 4;
      const int jg = j0 + rowb;
#pragma unroll
      for (int q = 0; q < 4; ++q) {
        const int col = wc * 64 + q * 16 + l15;
        const float4 vq = *(const float4*)(vTb + (size_t)col * NN + jg);
#pragma unroll
        for (int r = 0; r < 4; ++r) {
          const int j = rowb + r;
          const float x = acc[a][q][r] + uval[q] + ((const float*)&vq)[r];
          outp[obase + (size_t)j * OC + col] = sigf(x);
        }
      }
    }
  }
}

// ---------------------------------------------------------------------------
extern "C" void kernel_launch(void* const* d_in, const int* in_sizes, int n_in,
                              void* d_out, int out_size, void* d_ws,
                              size_t ws_size, hipStream_t stream) {
  const float* x0 = (const float*)d_in[0];
  const float* x1 = (const float*)d_in[1];
  const float* x2 = (const float*)d_in[2];
  const float *Wp[3][3], *bp[3][3];
  for (int l = 0; l < 3; ++l)
    for (int o = 0; o < 3; ++o) {
      Wp[l][o] = (const float*)d_in[3 + l * 6 + o * 2];
      bp[l][o] = (const float*)d_in[3 + l * 6 + o * 2 + 1];
    }

  const size_t F2E = (size_t)NB * NN * NN * OC;
  const size_t X2E = (size_t)NB * NN * NN * 64;

  uint8_t* ws = (uint8_t*)d_ws;
  size_t off = 0;
  auto carve = [&](size_t bytes) -> uint8_t* {
    uint8_t* p = ws + off;
    off += (bytes + 255) & ~(size_t)255;
    return p;
  };
  float* f0a = (float*)carve((size_t)NB * OC * 4);
  float* f0b = (float*)carve((size_t)NB * OC * 4);
  float* f1a = (float*)carve((size_t)NB * NN * OC * 4);
  float* f1b = (float*)carve((size_t)NB * NN * OC * 4);
  float* r2b = (float*)carve((size_t)NB * NN * 256 * 4);
  float* r2c = (float*)carve((size_t)NB * NN * 256 * 4);
  float* uu  = (float*)carve((size_t)NB * NN * OC * 4);
  float* vT  = (float*)carve((size_t)NB * OC * NN * 4);
  uint16_t* Wt0 = (uint16_t*)carve((size_t)OC * 128 * 2);
  uint16_t* Wt1 = (uint16_t*)carve((size_t)OC * 256 * 2);
  uint16_t* Wt2 = (uint16_t*)carve((size_t)OC * 256 * 2);
  uint16_t* Bt0 = (uint16_t*)carve((size_t)384 * 256 * 2);
  uint16_t* Bt1 = (uint16_t*)carve((size_t)384 * 512 * 2);
  uint16_t* Bt2 = (uint16_t*)carve((size_t)384 * 512 * 2);
  uint16_t* g1bf0 = (uint16_t*)carve((size_t)NB * NN * 256 * 2);
  uint16_t* g1bf1 = (uint16_t*)carve((size_t)NB * NN * 512 * 2);
  uint16_t* g1bf2 = (uint16_t*)carve((size_t)NB * NN * 512 * 2);
  __hip_bfloat16* f2a = (__hip_bfloat16*)carve(F2E * 2);

  __hip_bfloat16* f2b;
  uint16_t* x2bf;
  if (ws_size >= off + F2E * 2) {
    f2b = (__hip_bfloat16*)carve(F2E * 2);
    x2bf = (uint16_t*)f2b;  // aliases f2b; dead before f2b becomes live
  } else {
    f2b = (__hip_bfloat16*)d_in[2];  // x2 fully consumed in layer 0
    x2bf = (uint16_t*)carve(X2E * 2);
  }

  float* out_f0 = (float*)d_out;
  float* out_f1 = out_f0 + (size_t)NB * OC;
  float* out_f2 = out_f1 + (size_t)NB * NN * OC;

  prep_reduce<<<4800 + NB * NN, 256, 0, stream>>>(
      Wp[0][2], Wp[1][2], Wp[2][2], Wp[0][1], Wp[1][1], Wp[2][1], x0, x1, Wt0,
      Wt1, Wt2, Bt0, Bt1, Bt2, g1bf0, r2b, r2c, x2, x2bf);

  // ---- layer 0 (d0=32, d1=64, d2=64; KP=256) ----
  small_gemm<256, 32, 64, true><<<52, 256, 0, stream>>>(
      g1bf0, Bt0, bp[0][1], bp[0][2], f1a, g1bf1, uu, vT, x0, x1, Wp[0][0],
      bp[0][0], f0a);
  gemm2_kernel<64, __hip_bfloat16, true><<<NB * NN * 2, 256, 0, stream>>>(
      (const __hip_bfloat16*)x2bf, Wt0, uu, vT, f2a, r2b);
  conv_r2_kernel<<<NB * NN, 256, 0, stream>>>(r2b, g1bf1);

  // ---- layer 1 (all dims 128; KP=512) ----
  small_gemm<512, 128, 128, true><<<52, 256, 0, stream>>>(
      g1bf1, Bt1, bp[1][1], bp[1][2], f1b, g1bf2, uu, vT, f0a, f1a, Wp[1][0],
      bp[1][0], f0b);
  gemm2_kernel<128, __hip_bfloat16, true><<<NB * NN * 2, 256, 0, stream>>>(
      f2a, Wt1, uu, vT, f2b, r2c);
  conv_r2_kernel<<<NB * NN, 256, 0, stream>>>(r2c, g1bf2);

  // ---- layer 2 (outputs straight to d_out) ----
  small_gemm<512, 128, 128, false><<<52, 256, 0, stream>>>(
      g1bf2, Bt2, bp[2][1], bp[2][2], out_f1, nullptr, uu, vT, f0b, f1b,
      Wp[2][0], bp[2][0], out_f0);
  gemm2_kernel<128, float, false><<<NB * NN * 2, 256, 0, stream>>>(
      f2b, Wt2, uu, vT, out_f2, nullptr);
}

// Round 7
// 513.366 us; speedup vs baseline: 1.4396x; 1.0247x over previous
//
#include <hip/hip_runtime.h>
#include <hip/hip_bf16.h>
#include <cstdint>

#define NN 256
#define NB 4
#define OC 128

using bf16x8_t = __attribute__((ext_vector_type(8))) __bf16;
using f32x4_t  = __attribute__((ext_vector_type(4))) float;

typedef const __attribute__((address_space(1))) uint8_t* gptr1_t;
typedef __attribute__((address_space(3))) uint8_t* lptr3_t;

__device__ __forceinline__ void async_load16(const void* g, void* l) {
  __builtin_amdgcn_global_load_lds((gptr1_t)g, (lptr3_t)l, 16, 0, 0);
}

// sigmoid via v_rcp_f32 (1-ulp) instead of the precise-div sequence
__device__ __forceinline__ float sigf(float x) {
  return __builtin_amdgcn_rcpf(1.0f + __expf(-x));
}

__device__ __forceinline__ uint16_t f2bf_rne(float f) {
  uint32_t u = __float_as_uint(f);
  uint32_t r = (u + 0x7fffu + ((u >> 16) & 1u)) >> 16;
  return (uint16_t)r;
}

// ---------------------------------------------------------------------------
// prep (weights transpose/pack, g1bf0 static slots, r2 init)  +  reduce2 L0.
// ---------------------------------------------------------------------------
__device__ __forceinline__ void emit_wt(const float* __restrict__ W2,
                                        uint16_t* __restrict__ Wt, int d1,
                                        int d2, int idx) {
  const int K = 2 * d2;
  const int nn = idx / K, k = idx - nn * K;
  const int row = (k < d2) ? (d1 + k) : (2 * d1 + d2 + (k - d2));
  Wt[idx] = f2bf_rne(W2[row * OC + nn]);
}

__device__ __forceinline__ void emit_bt(const float* __restrict__ W1,
                                        const float* __restrict__ W2,
                                        uint16_t* __restrict__ Bt, int D0,
                                        int D1, int D2, int FIN1, int KP,
                                        int idx) {
  const int n = idx / KP, k = idx - n * KP;
  float val = 0.f;
  if (n < 128) {
    if (k < FIN1) val = W1[k * OC + n];
  } else if (n < 256) {
    if (k >= D0 && k < D0 + D1) val = W2[(k - D0) * OC + (n - 128)];
  } else {
    if (k >= D0 && k < D0 + D1) val = W2[(D1 + D2 + (k - D0)) * OC + (n - 256)];
  }
  Bt[idx] = f2bf_rne(val);
}

__global__ __launch_bounds__(256) void prep_reduce(
    const float* __restrict__ W2_0, const float* __restrict__ W2_1,
    const float* __restrict__ W2_2, const float* __restrict__ W1_0,
    const float* __restrict__ W1_1, const float* __restrict__ W1_2,
    const float* __restrict__ x0, const float* __restrict__ x1,
    uint16_t* __restrict__ Wt0, uint16_t* __restrict__ Wt1,
    uint16_t* __restrict__ Wt2, uint16_t* __restrict__ Bt0,
    uint16_t* __restrict__ Bt1, uint16_t* __restrict__ Bt2,
    uint16_t* __restrict__ g1bf0, float* __restrict__ r2b,
    float* __restrict__ r2c, const float* __restrict__ x2,
    uint16_t* __restrict__ x2bf) {
  __shared__ float4 smx[256], smn[256];
  const int blk = blockIdx.x;
  const int tid = threadIdx.x;

  if (blk < 4800) {  // ---- prep part ----
    int g = blk * 256 + tid;
    if (g < 16384) { emit_wt(W2_0, Wt0, 64, 64, g); return; }
    g -= 16384;
    if (g < 32768) { emit_wt(W2_1, Wt1, 128, 128, g); return; }
    g -= 32768;
    if (g < 32768) { emit_wt(W2_2, Wt2, 128, 128, g); return; }
    g -= 32768;
    if (g < 98304) { emit_bt(W1_0, W2_0, Bt0, 32, 64, 64, 224, 256, g); return; }
    g -= 98304;
    if (g < 196608) { emit_bt(W1_1, W2_1, Bt1, 128, 128, 128, 512, 512, g); return; }
    g -= 196608;
    if (g < 196608) { emit_bt(W1_2, W2_2, Bt2, 128, 128, 128, 512, 512, g); return; }
    g -= 196608;
    if (g < 131072) {  // g1bf0 static slots: f0[0..32) f1[32..96) pad[224..256)
      const int row = g >> 7, t = g & 127;
      uint16_t* const gp = g1bf0 + (size_t)row * 256;
      if (t < 32) gp[t] = f2bf_rne(x0[(row >> 8) * 32 + t]);
      else if (t < 96) gp[t] = f2bf_rne(x1[(size_t)row * 64 + (t - 32)]);
      else gp[128 + t] = 0;
      return;
    }
    g -= 131072;
    if (g < 262144) { r2b[g] = ((g & 255) < 128) ? 0.f : 1.f; return; }
    g -= 262144;
    if (g < 262144) { r2c[g] = ((g & 255) < 128) ? 0.f : 1.f; }
    return;
  }

  // ---- reduce2 layer 0: fp32 x2 -> bf16 x2bf + max/min into g1bf0 ----
  const int bid = blk - 4800;               // b*256 + i
  const int i = bid & 255;
  const int q = tid & 15, s = tid >> 4;
  const size_t rowbase = ((size_t)bid * NN) * 64 + q * 4;
  float mxA0 = 0.f, mxA1 = 0.f, mxA2 = 0.f, mxA3 = 0.f;
  float mnA0 = 1.f, mnA1 = 1.f, mnA2 = 1.f, mnA3 = 1.f;
  float mxB0 = 0.f, mxB1 = 0.f, mxB2 = 0.f, mxB3 = 0.f;
  float mnB0 = 1.f, mnB1 = 1.f, mnB2 = 1.f, mnB3 = 1.f;
#pragma unroll 2
  for (int t = 0; t < 16; t += 2) {
    const int jA = s + t * 16, jB = jA + 16;
    const float4 xa = *(const float4*)(x2 + rowbase + (size_t)jA * 64);
    const float4 xb = *(const float4*)(x2 + rowbase + (size_t)jB * 64);
    uint2 pa, pb;
    pa.x = (uint32_t)f2bf_rne(xa.x) | ((uint32_t)f2bf_rne(xa.y) << 16);
    pa.y = (uint32_t)f2bf_rne(xa.z) | ((uint32_t)f2bf_rne(xa.w) << 16);
    pb.x = (uint32_t)f2bf_rne(xb.x) | ((uint32_t)f2bf_rne(xb.y) << 16);
    pb.y = (uint32_t)f2bf_rne(xb.z) | ((uint32_t)f2bf_rne(xb.w) << 16);
    *(uint2*)(x2bf + rowbase + (size_t)jA * 64) = pa;
    *(uint2*)(x2bf + rowbase + (size_t)jB * 64) = pb;
    if (jA != i) {
      mxA0 = fmaxf(mxA0, xa.x); mxA1 = fmaxf(mxA1, xa.y);
      mxA2 = fmaxf(mxA2, xa.z); mxA3 = fmaxf(mxA3, xa.w);
      mnA0 = fminf(mnA0, xa.x); mnA1 = fminf(mnA1, xa.y);
      mnA2 = fminf(mnA2, xa.z); mnA3 = fminf(mnA3, xa.w);
    }
    if (jB != i) {
      mxB0 = fmaxf(mxB0, xb.x); mxB1 = fmaxf(mxB1, xb.y);
      mxB2 = fmaxf(mxB2, xb.z); mxB3 = fmaxf(mxB3, xb.w);
      mnB0 = fminf(mnB0, xb.x); mnB1 = fminf(mnB1, xb.y);
      mnB2 = fminf(mnB2, xb.z); mnB3 = fminf(mnB3, xb.w);
    }
  }
  float mx0 = fmaxf(mxA0, mxB0), mx1 = fmaxf(mxA1, mxB1);
  float mx2 = fmaxf(mxA2, mxB2), mx3 = fmaxf(mxA3, mxB3);
  float mn0 = fminf(mnA0, mnB0), mn1 = fminf(mnA1, mnB1);
  float mn2 = fminf(mnA2, mnB2), mn3 = fminf(mnA3, mnB3);
  smx[tid] = make_float4(mx0, mx1, mx2, mx3);
  smn[tid] = make_float4(mn0, mn1, mn2, mn3);
  __syncthreads();
  if (s == 0) {
    for (int ss = 1; ss < 16; ++ss) {
      float4 a = smx[q + ss * 16], c = smn[q + ss * 16];
      mx0 = fmaxf(mx0, a.x); mx1 = fmaxf(mx1, a.y);
      mx2 = fmaxf(mx2, a.z); mx3 = fmaxf(mx3, a.w);
      mn0 = fminf(mn0, c.x); mn1 = fminf(mn1, c.y);
      mn2 = fminf(mn2, c.z); mn3 = fminf(mn3, c.w);
    }
    uint16_t* const g = g1bf0 + (size_t)bid * 256;
    g[96 + q * 4 + 0] = f2bf_rne(mx0); g[96 + q * 4 + 1] = f2bf_rne(mx1);
    g[96 + q * 4 + 2] = f2bf_rne(mx2); g[96 + q * 4 + 3] = f2bf_rne(mx3);
    g[160 + q * 4 + 0] = f2bf_rne(mn0); g[160 + q * 4 + 1] = f2bf_rne(mn1);
    g[160 + q * 4 + 2] = f2bf_rne(mn2); g[160 + q * 4 + 3] = f2bf_rne(mn3);
  }
}

// ---------------------------------------------------------------------------
// Small fused MFMA GEMM + o0 (round-0 proven LDS-staged structure).
// R2FUSE: for KP=512, A-chunks with kbg>=256 are the r2 slot -- instead of
// reading pre-converted g1next (which required a separate conv_r2 launch),
// reg-stage from fp32 r2 directly: float4x2 -> f2bf_rne pack -> ds_write.
// Bit-identical to the old conv_r2 path; removes 2 launches + 2 gaps.
// ---------------------------------------------------------------------------
template <int KP, int D0, int D1, bool DUP, bool R2FUSE>
__global__ __launch_bounds__(256) void small_gemm(
    const uint16_t* __restrict__ g1, const uint16_t* __restrict__ Bt,
    const float* __restrict__ b1, const float* __restrict__ b2,
    float* __restrict__ f1out, uint16_t* __restrict__ g1next,
    float* __restrict__ u, float* __restrict__ vT,
    const float* __restrict__ f0in, const float* __restrict__ f1in,
    const float* __restrict__ W0, const float* __restrict__ b0,
    float* __restrict__ f0out, const float* __restrict__ r2src) {
  constexpr int NCH = KP / 64;
  const int bid = blockIdx.x;
  const int tid = threadIdx.x;

  __shared__ __align__(16) uint8_t ldsA[8192];
  __shared__ __align__(16) uint8_t ldsB[16384];

  if (bid < 48) {
    const int mt = bid / 3, nt = bid - mt * 3;
    const int m0 = mt * 64, n0 = nt * 128;
    const int wv = tid >> 6, lane = tid & 63;
    const int l15 = lane & 15, l4 = lane >> 4;

    f32x4_t acc[4][2];
#pragma unroll
    for (int a = 0; a < 4; ++a)
#pragma unroll
      for (int q = 0; q < 2; ++q) acc[a][q] = (f32x4_t){0.f, 0.f, 0.f, 0.f};

    for (int c = 0; c < NCH; ++c) {
      const int kbg = c * 64;
#pragma unroll
      for (int t = 0; t < 2; ++t) {  // A units: id = ks*4 + mi
        const int id = wv * 2 + t;
        const int mi = id & 3, ks = id >> 2;
        if (R2FUSE && kbg >= KP / 2) {
          // r2 slot: reg-stage fp32 -> bf16 (replaces conv_r2 kernel)
          const float* const src = r2src +
              (size_t)(m0 + mi * 16 + l15) * (KP / 2) + (kbg - KP / 2) +
              ks * 32 + l4 * 8;
          const float4 fa = *(const float4*)(src);
          const float4 fb = *(const float4*)(src + 4);
          uint4 v;
          v.x = (uint32_t)f2bf_rne(fa.x) | ((uint32_t)f2bf_rne(fa.y) << 16);
          v.y = (uint32_t)f2bf_rne(fa.z) | ((uint32_t)f2bf_rne(fa.w) << 16);
          v.z = (uint32_t)f2bf_rne(fb.x) | ((uint32_t)f2bf_rne(fb.y) << 16);
          v.w = (uint32_t)f2bf_rne(fb.z) | ((uint32_t)f2bf_rne(fb.w) << 16);
          *(uint4*)(ldsA + id * 1024 + (lane << 4)) = v;
        } else {
          async_load16(
              g1 + (size_t)(m0 + mi * 16 + l15) * KP + kbg + ks * 32 + l4 * 8,
              ldsA + id * 1024);
        }
      }
#pragma unroll
      for (int t = 0; t < 4; ++t) {  // B units: id = ks*8 + ni
        const int id = wv * 4 + t;
        const int ni = id & 7, ks = id >> 3;
        async_load16(Bt + (size_t)(n0 + ni * 16 + l15) * KP + kbg + ks * 32 + l4 * 8,
                     ldsB + id * 1024);
      }
      __syncthreads();
#pragma unroll
      for (int ks = 0; ks < 2; ++ks) {
        bf16x8_t Af[4], Bf[2];
#pragma unroll
        for (int a = 0; a < 4; ++a)
          Af[a] = *(const bf16x8_t*)(ldsA + ((ks * 4 + a) << 10) + (lane << 4));
#pragma unroll
        for (int q = 0; q < 2; ++q)
          Bf[q] = *(const bf16x8_t*)(ldsB + ((ks * 8 + wv * 2 + q) << 10) + (lane << 4));
#pragma unroll
        for (int a = 0; a < 4; ++a)
#pragma unroll
          for (int q = 0; q < 2; ++q)
            acc[a][q] = __builtin_amdgcn_mfma_f32_16x16x32_bf16(Af[a], Bf[q],
                                                                acc[a][q], 0, 0, 0);
      }
      __syncthreads();
    }

    float bias[2];
#pragma unroll
    for (int q = 0; q < 2; ++q) {
      const int cc = wv * 32 + q * 16 + l15;
      bias[q] = (nt == 0) ? b1[cc] : ((nt == 1) ? b2[cc] : 0.f);
    }
#pragma unroll
    for (int a = 0; a < 4; ++a) {
      const int rl = a * 16 + l4 * 4;
#pragma unroll
      for (int r = 0; r < 4; ++r) {
        const size_t bi = m0 + rl + r;
#pragma unroll
        for (int q = 0; q < 2; ++q) {
          const int cc = wv * 32 + q * 16 + l15;
          const float x = acc[a][q][r] + bias[q];
          if (nt == 0) {
            const float val = sigf(x);
            f1out[bi * OC + cc] = val;
            if (DUP) g1next[bi * 512 + 128 + cc] = f2bf_rne(val);
          } else if (nt == 1) {
            u[bi * OC + cc] = x;
          } else {
            const int b = (int)(bi >> 8), j = (int)(bi & 255);
            vT[((size_t)b * OC + cc) * NN + j] = x;
          }
        }
      }
    }
  } else {
    // ---- o0 for batch b ----
    constexpr int FIN0 = D0 + 2 * D1;
    constexpr int S = 256 / D1;
    const int b = bid - 48;
    float* const sm = (float*)ldsA;   // reuse LDS: g0 | smx | smn | sval
    float* const g0 = sm;
    float* const smx = sm + 512;
    float* const smn = sm + 768;
    float* const sval = sm + 1024;
    const int cc = tid & (D1 - 1), ss = tid / D1;
    float mx = -1e30f, mn = 1e30f;
    const float* f1b = f1in + (size_t)b * NN * D1;
    for (int j = ss; j < NN; j += S) {
      const float x = f1b[(size_t)j * D1 + cc];
      mx = fmaxf(mx, x); mn = fminf(mn, x);
    }
    smx[tid] = mx; smn[tid] = mn;
    __syncthreads();
    if (ss == 0) {
      for (int s2 = 1; s2 < S; ++s2) {
        mx = fmaxf(mx, smx[cc + s2 * D1]);
        mn = fminf(mn, smn[cc + s2 * D1]);
      }
      g0[D0 + cc] = mx;
      g0[D0 + D1 + cc] = mn;
    }
    if (tid < D0) g0[tid] = f0in[b * D0 + tid];
    __syncthreads();
    if (tid < OC) {
      float acc = b0[tid];
#pragma unroll 8
      for (int k = 0; k < FIN0; ++k) acc += g0[k] * W0[k * OC + tid];
      const float val = sigf(acc);
      f0out[b * OC + tid] = val;
      sval[tid] = val;
    }
    if (DUP) {
      __syncthreads();
      for (int idx = tid; idx < 256 * 128; idx += 256) {
        const int row = idx >> 7, c2 = idx & 127;
        g1next[((size_t)(b * 256 + row)) * 512 + c2] = f2bf_rne(sval[c2]);
      }
    }
  }
}

// ---------------------------------------------------------------------------
// Big order-2 GEMM (R2-best structure: K as 32-wide chunks, double-buffered
// global_load_lds staging, counted vmcnt(4) so next chunk's loads stay in
// flight across raw s_barriers).
// NOTE (R0-R6 finding): four structurally different staged variants (chunked,
// dbuf, bulk-prefetch, contiguous 2-phase) all measure ~80 us/dispatch;
// occupancy 10-77% and pipeline depth 2-32 loads are irrelevant. Models
// predict 15-30 us; the gap is unexplained -- do not re-try schedule variants.
// ---------------------------------------------------------------------------
template <int D2, typename OUT_T, bool REDUCE>
__global__ __launch_bounds__(256, 4) void gemm2_kernel(
    const __hip_bfloat16* __restrict__ f2, const uint16_t* __restrict__ Wt,
    const float* __restrict__ u, const float* __restrict__ vT,
    OUT_T* __restrict__ out, float* __restrict__ r2n) {
  constexpr int K = 2 * D2;
  constexpr int NCH = K / 32;
  constexpr bool BF16OUT = (sizeof(OUT_T) == 2);
  constexpr int LDSB = BF16OUT ? (128 * 272) : 32768;
  const int bid = blockIdx.x;
  const int jt = bid & 1, i = (bid >> 1) & 255, b = bid >> 9;
  const int j0 = jt * 128;
  const int tid = threadIdx.x;
  const int wv = tid >> 6, lane = tid & 63;
  const int wr = wv >> 1, wc = wv & 1;
  const int l15 = lane & 15, l4 = lane >> 4;

  __shared__ __align__(16) uint8_t lds[LDSB];
  __shared__ unsigned smax[128], smin[128];

  const __hip_bfloat16* const A1 = f2 + ((size_t)(b * NN + i) * NN + j0) * D2;
  const __hip_bfloat16* const A2 = f2 + ((size_t)(b * NN + j0) * NN + i) * D2;

  f32x4_t acc[4][4];
#pragma unroll
  for (int a = 0; a < 4; ++a)
#pragma unroll
    for (int q = 0; q < 4; ++q) acc[a][q] = (f32x4_t){0.f, 0.f, 0.f, 0.f};

  // stage chunk c (32-wide K) into buffer buf: 2 A units + 2 W units per wave
  auto STAGE = [&](int c, int buf) {
    const int kbg = c * 32;
    uint8_t* const bA = lds + buf * 16384;
    uint8_t* const bW = bA + 8192;
    const bool second = (kbg >= D2);
    const __hip_bfloat16* const Ab = second ? A2 : A1;
    const size_t rstride = second ? (size_t)NN * D2 : (size_t)D2;
    const int kbase = second ? (kbg - D2) : kbg;
#pragma unroll
    for (int t = 0; t < 2; ++t) {
      const int mi = wv * 2 + t;  // row-block 0..7
      async_load16(Ab + (size_t)(mi * 16 + l15) * rstride + kbase + l4 * 8,
                   bA + mi * 1024);
    }
#pragma unroll
    for (int t = 0; t < 2; ++t) {
      const int ni = wv * 2 + t;  // col-block 0..7
      async_load16(Wt + (size_t)(ni * 16 + l15) * K + kbg + l4 * 8,
                   bW + ni * 1024);
    }
  };

  auto COMPUTE = [&](int buf) {
    const uint8_t* const bA = lds + buf * 16384;
    const uint8_t* const bW = bA + 8192;
    bf16x8_t Af[4], Bf[4];
#pragma unroll
    for (int a = 0; a < 4; ++a)
      Af[a] = *(const bf16x8_t*)(bA + ((wr * 4 + a) << 10) + (lane << 4));
#pragma unroll
    for (int q = 0; q < 4; ++q)
      Bf[q] = *(const bf16x8_t*)(bW + ((wc * 4 + q) << 10) + (lane << 4));
#pragma unroll
    for (int a = 0; a < 4; ++a)
#pragma unroll
      for (int q = 0; q < 4; ++q)
        acc[a][q] = __builtin_amdgcn_mfma_f32_16x16x32_bf16(Af[a], Bf[q],
                                                            acc[a][q], 0, 0, 0);
  };

  STAGE(0, 0);
#pragma unroll
  for (int c = 0; c < NCH - 1; ++c) {
    STAGE(c + 1, (c + 1) & 1);
    asm volatile("s_waitcnt vmcnt(4)" ::: "memory");  // chunk c landed; c+1 in flight
    __builtin_amdgcn_sched_barrier(0);
    __builtin_amdgcn_s_barrier();
    __builtin_amdgcn_sched_barrier(0);
    COMPUTE(c & 1);
    asm volatile("s_waitcnt lgkmcnt(0)" ::: "memory");  // own ds_reads done
    __builtin_amdgcn_sched_barrier(0);
    __builtin_amdgcn_s_barrier();  // buffer (c&1) now safe to overwrite
    __builtin_amdgcn_sched_barrier(0);
  }
  asm volatile("s_waitcnt vmcnt(0)" ::: "memory");
  __builtin_amdgcn_sched_barrier(0);
  __builtin_amdgcn_s_barrier();
  __builtin_amdgcn_sched_barrier(0);
  COMPUTE((NCH - 1) & 1);
  __syncthreads();  // full drain before LDS reuse by epilogue

  const size_t bi2 = (size_t)(b * NN + i);
  float uval[4];
#pragma unroll
  for (int q = 0; q < 4; ++q) uval[q] = u[bi2 * OC + wc * 64 + q * 16 + l15];
  const size_t obase = (bi2 * NN + j0) * OC;
  const float* const vTb = vT + (size_t)b * OC * NN;

  if (BF16OUT) {
    if (REDUCE && tid < 128) { smax[tid] = 0u; smin[tid] = 0x3f800000u; }
    __syncthreads();
    float lmx[4] = {0.f, 0.f, 0.f, 0.f};
    float lmn[4] = {1.f, 1.f, 1.f, 1.f};
#pragma unroll
    for (int a = 0; a < 4; ++a) {
      const int rowb = wr * 64 + a * 16 + l4 * 4;
      const int jg = j0 + rowb;
#pragma unroll
      for (int q = 0; q < 4; ++q) {
        const int col = wc * 64 + q * 16 + l15;
        const float4 vq = *(const float4*)(vTb + (size_t)col * NN + jg);
#pragma unroll
        for (int r = 0; r < 4; ++r) {
          const int j = rowb + r;
          const float x = acc[a][q][r] + uval[q] + ((const float*)&vq)[r];
          const float sg = sigf(x);
          *(uint16_t*)(lds + j * 272 + col * 2) = f2bf_rne(sg);
          if (REDUCE && (jg + r) != i) {
            lmx[q] = fmaxf(lmx[q], sg);
            lmn[q] = fminf(lmn[q], sg);
          }
        }
      }
    }
    if (REDUCE) {
#pragma unroll
      for (int q = 0; q < 4; ++q) {
        const int col = wc * 64 + q * 16 + l15;
        atomicMax(&smax[col], __float_as_uint(lmx[q]));
        atomicMin(&smin[col], __float_as_uint(lmn[q]));
      }
    }
    __syncthreads();
    uint16_t* const outp = (uint16_t*)out;
#pragma unroll
    for (int ci = 0; ci < 8; ++ci) {
      const int chunk = ci * 256 + tid;
      const int row = chunk >> 4, off = chunk & 15;
      const uint4 val = *(const uint4*)(lds + row * 272 + off * 16);
      *(uint4*)(outp + obase + (size_t)row * OC + off * 8) = val;
    }
    if (REDUCE && tid < 128) {
      unsigned* const r2u = (unsigned*)r2n;
      atomicMax(&r2u[bi2 * 256 + tid], smax[tid]);
      atomicMin(&r2u[bi2 * 256 + 128 + tid], smin[tid]);
    }
  } else {
    float* const outp = (float*)out;
#pragma unroll
    for (int a = 0; a < 4; ++a) {
      const int rowb = wr * 64 + a * 16 + l4 * 4;
      const int jg = j0 + rowb;
#pragma unroll
      for (int q = 0; q < 4; ++q) {
        const int col = wc * 64 + q * 16 + l15;
        const float4 vq = *(const float4*)(vTb + (size_t)col * NN + jg);
#pragma unroll
        for (int r = 0; r < 4; ++r) {
          const int j = rowb + r;
          const float x = acc[a][q][r] + uval[q] + ((const float*)&vq)[r];
          outp[obase + (size_t)j * OC + col] = sigf(x);
        }
      }
    }
  }
}

// ---------------------------------------------------------------------------
extern "C" void kernel_launch(void* const* d_in, const int* in_sizes, int n_in,
                              void* d_out, int out_size, void* d_ws,
                              size_t ws_size, hipStream_t stream) {
  const float* x0 = (const float*)d_in[0];
  const float* x1 = (const float*)d_in[1];
  const float* x2 = (const float*)d_in[2];
  const float *Wp[3][3], *bp[3][3];
  for (int l = 0; l < 3; ++l)
    for (int o = 0; o < 3; ++o) {
      Wp[l][o] = (const float*)d_in[3 + l * 6 + o * 2];
      bp[l][o] = (const float*)d_in[3 + l * 6 + o * 2 + 1];
    }

  const size_t F2E = (size_t)NB * NN * NN * OC;
  const size_t X2E = (size_t)NB * NN * NN * 64;

  uint8_t* ws = (uint8_t*)d_ws;
  size_t off = 0;
  auto carve = [&](size_t bytes) -> uint8_t* {
    uint8_t* p = ws + off;
    off += (bytes + 255) & ~(size_t)255;
    return p;
  };
  float* f0a = (float*)carve((size_t)NB * OC * 4);
  float* f0b = (float*)carve((size_t)NB * OC * 4);
  float* f1a = (float*)carve((size_t)NB * NN * OC * 4);
  float* f1b = (float*)carve((size_t)NB * NN * OC * 4);
  float* r2b = (float*)carve((size_t)NB * NN * 256 * 4);
  float* r2c = (float*)carve((size_t)NB * NN * 256 * 4);
  float* uu  = (float*)carve((size_t)NB * NN * OC * 4);
  float* vT  = (float*)carve((size_t)NB * OC * NN * 4);
  uint16_t* Wt0 = (uint16_t*)carve((size_t)OC * 128 * 2);
  uint16_t* Wt1 = (uint16_t*)carve((size_t)OC * 256 * 2);
  uint16_t* Wt2 = (uint16_t*)carve((size_t)OC * 256 * 2);
  uint16_t* Bt0 = (uint16_t*)carve((size_t)384 * 256 * 2);
  uint16_t* Bt1 = (uint16_t*)carve((size_t)384 * 512 * 2);
  uint16_t* Bt2 = (uint16_t*)carve((size_t)384 * 512 * 2);
  uint16_t* g1bf0 = (uint16_t*)carve((size_t)NB * NN * 256 * 2);
  uint16_t* g1bf1 = (uint16_t*)carve((size_t)NB * NN * 512 * 2);
  uint16_t* g1bf2 = (uint16_t*)carve((size_t)NB * NN * 512 * 2);
  __hip_bfloat16* f2a = (__hip_bfloat16*)carve(F2E * 2);

  __hip_bfloat16* f2b;
  uint16_t* x2bf;
  if (ws_size >= off + F2E * 2) {
    f2b = (__hip_bfloat16*)carve(F2E * 2);
    x2bf = (uint16_t*)f2b;  // aliases f2b; dead before f2b becomes live
  } else {
    f2b = (__hip_bfloat16*)d_in[2];  // x2 fully consumed in layer 0
    x2bf = (uint16_t*)carve(X2E * 2);
  }

  float* out_f0 = (float*)d_out;
  float* out_f1 = out_f0 + (size_t)NB * OC;
  float* out_f2 = out_f1 + (size_t)NB * NN * OC;

  prep_reduce<<<4800 + NB * NN, 256, 0, stream>>>(
      Wp[0][2], Wp[1][2], Wp[2][2], Wp[0][1], Wp[1][1], Wp[2][1], x0, x1, Wt0,
      Wt1, Wt2, Bt0, Bt1, Bt2, g1bf0, r2b, r2c, x2, x2bf);

  // ---- layer 0 (d0=32, d1=64, d2=64; KP=256) ----
  small_gemm<256, 32, 64, true, false><<<52, 256, 0, stream>>>(
      g1bf0, Bt0, bp[0][1], bp[0][2], f1a, g1bf1, uu, vT, x0, x1, Wp[0][0],
      bp[0][0], f0a, nullptr);
  gemm2_kernel<64, __hip_bfloat16, true><<<NB * NN * 2, 256, 0, stream>>>(
      (const __hip_bfloat16*)x2bf, Wt0, uu, vT, f2a, r2b);

  // ---- layer 1 (all dims 128; KP=512; r2 read fused from r2b) ----
  small_gemm<512, 128, 128, true, true><<<52, 256, 0, stream>>>(
      g1bf1, Bt1, bp[1][1], bp[1][2], f1b, g1bf2, uu, vT, f0a, f1a, Wp[1][0],
      bp[1][0], f0b, r2b);
  gemm2_kernel<128, __hip_bfloat16, true><<<NB * NN * 2, 256, 0, stream>>>(
      f2a, Wt1, uu, vT, f2b, r2c);

  // ---- layer 2 (outputs straight to d_out; r2 read fused from r2c) ----
  small_gemm<512, 128, 128, false, true><<<52, 256, 0, stream>>>(
      g1bf2, Bt2, bp[2][1], bp[2][2], out_f1, nullptr, uu, vT, f0b, f1b,
      Wp[2][0], bp[2][0], out_f0, r2c);
  gemm2_kernel<128, float, false><<<NB * NN * 2, 256, 0, stream>>>(
      f2b, Wt2, uu, vT, out_f2, nullptr);
}